// Round 11
// baseline (1333.743 us; speedup 1.0000x reference)
//
#include <hip/hip_runtime.h>
#include <stdint.h>

#define T_TOK 4096
#define H_DIM 2048
#define I_DIM 4096
#define N_EXP 8

typedef __attribute__((ext_vector_type(8))) short bf16x8;     // MFMA A/B frag (8 bf16)
typedef __attribute__((ext_vector_type(4))) float f32x4;      // MFMA C/D frag
typedef __attribute__((ext_vector_type(8))) unsigned short u16x8;

// f32->bf16 RNE via integer emulation. NOTE (r7/r9 post-mortem): gfx950's
// v_cvt_pk_bf16_f32 and __builtin_convertvector to __bf16 do NOT match
// numpy's round-to-nearest-even (absmax 0.19-0.31 vs 0.0156) — keep this.
__device__ __forceinline__ unsigned short f2bf(float x) {
    union { float f; unsigned u; } v; v.f = x;
    unsigned r = v.u + 0x7FFF + ((v.u >> 16) & 1);   // RNE
    return (unsigned short)(r >> 16);
}

__device__ __forceinline__ u16x8 cvt8(float4 a, float4 b) {
    u16x8 o;
    o[0] = f2bf(a.x); o[1] = f2bf(a.y); o[2] = f2bf(a.z); o[3] = f2bf(a.w);
    o[4] = f2bf(b.x); o[5] = f2bf(b.y); o[6] = f2bf(b.z); o[7] = f2bf(b.w);
    return o;
}

// Direct global->LDS async copy, 16B per lane. LDS dest = wave-uniform base + lane*16.
__device__ __forceinline__ void async_cp16(const void* g, const unsigned short* lds_base) {
    __builtin_amdgcn_global_load_lds(
        (const __attribute__((address_space(1))) unsigned*)g,
        (__attribute__((address_space(3))) unsigned*)(unsigned)(uintptr_t)lds_base,
        16, 0, 0);
}

// ---------------- routing: top-2 + softmax + bucketize (single block) ----------
__global__ void routing_kernel(const float* __restrict__ logits,
                               int* __restrict__ counts, int* __restrict__ offsets,
                               int* __restrict__ btok, float* __restrict__ bw,
                               int* __restrict__ tok2slot) {
    __shared__ int s_cnt[N_EXP];
    __shared__ int s_off[N_EXP];
    __shared__ int s_cur[N_EXP];
    const int tid = threadIdx.x;   // 256 threads, 16 tokens each
    if (tid < N_EXP) s_cnt[tid] = 0;
    __syncthreads();

    int e0a[16], e1a[16]; float w0a[16], w1a[16];
    #pragma unroll
    for (int it = 0; it < 16; ++it) {
        int t = tid + it * 256;
        float l[8];
        #pragma unroll
        for (int e = 0; e < 8; ++e) l[e] = logits[t * 8 + e];
        int b0 = 0; float v0 = l[0];
        #pragma unroll
        for (int e = 1; e < 8; ++e) if (l[e] > v0) { v0 = l[e]; b0 = e; }
        int b1 = (b0 == 0) ? 1 : 0; float v1 = l[b1];
        #pragma unroll
        for (int e = 0; e < 8; ++e) if (e != b0 && l[e] > v1) { v1 = l[e]; b1 = e; }
        float w0 = 1.0f / (1.0f + __expf(v1 - v0));
        e0a[it] = b0; e1a[it] = b1; w0a[it] = w0; w1a[it] = 1.0f - w0;
        atomicAdd(&s_cnt[b0], 1);
        atomicAdd(&s_cnt[b1], 1);
    }
    __syncthreads();
    if (tid == 0) {
        int acc = 0;
        for (int e = 0; e < N_EXP; ++e) { s_off[e] = acc; s_cur[e] = acc; acc += s_cnt[e]; }
    }
    __syncthreads();
    if (tid < N_EXP) { counts[tid] = s_cnt[tid]; offsets[tid] = s_off[tid]; }
    #pragma unroll
    for (int it = 0; it < 16; ++it) {
        int t = tid + it * 256;
        int p0 = atomicAdd(&s_cur[e0a[it]], 1);
        btok[p0] = t; bw[p0] = w0a[it];
        int p1 = atomicAdd(&s_cur[e1a[it]], 1);
        btok[p1] = t; bw[p1] = w1a[it];
        tok2slot[2 * t] = p0;
        tok2slot[2 * t + 1] = p1;
    }
}

// ---------------- fp32 -> bf16 convert (8 floats / thread) -------------------
__global__ void cvt_kernel(const float* __restrict__ x, unsigned short* __restrict__ xb) {
    int i = blockIdx.x * blockDim.x + threadIdx.x;   // over groups of 8 floats
    float4 a = ((const float4*)x)[2 * i];
    float4 b = ((const float4*)x)[2 * i + 1];
    ((u16x8*)xb)[i] = cvt8(a, b);
}

// =====================  PATH A: fused-convert, multi-block/CU GEMMs ==========
//
// Ring-3 K=32 phase schedule (round-6 proven, nt fast for A L2-reuse):
//   phase h: {cvt+ds_write B(h+2) (regs loaded phase h-1) into slot (h+2)%3
//             | reload regs with B(h+3) | ds_read frags (slot h%3)
//             | 2 A gload_lds (h+2) | sched_barrier | setprio(1) MFMA
//             | setprio(0) | lgkmcnt(0) | vmcnt(N) | barrier}
// Invariants:
//   - ds_write at top of phase h targets slot (h+2)%3 == (h-1)%3, whose
//     readers (phase h-1) drained at the previous lgkmcnt(0)+barrier.
//   - vmcnt(N) at end of phase h: only this phase's B-loads + 2 A-gloads
//     remain => A(h+1) landed, B(h+2) regs retired via cvt consumption.
// Swizzle (verified conflict-free): LDS slot p of row r holds global chunk
// p ^ ((r>>1)&3); A via pre-swizzled source + linear gload_lds dest,
// B via natural source chunk + swizzled ds_write; reads at q ^ ((c>>1)&3).
// (Row-group offsets 64/128/192 preserve (r>>1)&3, so one swizzle per thread.)

// GEMM1: h[slot,i] = silu(x@W1^T)*(x@W3^T). BM=128 x BN=128, 72KB, 2 blk/CU.
// 32 MFMA/wave/phase (16 gate + 16 up), NT=64.
__global__ __launch_bounds__(256, 2)
void gemm1p_kernel(const unsigned short* __restrict__ Xb,
                   const float* __restrict__ W1,
                   const float* __restrict__ W3,
                   const int* __restrict__ counts,
                   const int* __restrict__ offsets,
                   const int* __restrict__ btok,
                   unsigned short* __restrict__ hbuf) {
    const int e = blockIdx.z;
    const int ne = counts[e];
    const int mt = blockIdx.y;
    if (mt * 128 >= ne) return;
    const int nt = blockIdx.x;
    const int off = offsets[e];

    __shared__ unsigned short sA[3][128 * 32];    // 24 KB
    __shared__ unsigned short sB1[3][128 * 32];   // 24 KB
    __shared__ unsigned short sB3[3][128 * 32];   // 24 KB -> 72 KB total

    const int tid = threadIdx.x;
    const int lane = tid & 63;
    const int wv = tid >> 6;         // 0..3
    const int wm = (wv >> 1) << 6;   // {0,64}
    const int wn = (wv & 1) << 6;    // {0,64}
    const int q = lane >> 4;
    const int c = lane & 15;
    const int xq = q ^ ((c >> 1) & 3);          // swizzled read slot

    const int aoff = (wm + c) * 32 + xq * 8;
    const int boff = (wn + c) * 32 + xq * 8;

    // A staging: per wave 16 rows per gload; rows arow and arow+64
    const int arow = wv * 16 + (lane >> 2);           // 0..63
    const int sgA = (lane & 3) ^ ((lane >> 3) & 3);

    int sl0 = mt * 128 + arow;       if (sl0 >= ne) sl0 = ne - 1;
    int sl1 = mt * 128 + arow + 64;  if (sl1 >= ne) sl1 = ne - 1;
    const unsigned short* gA0 = Xb + (size_t)btok[off + sl0] * H_DIM + sgA * 8;
    const unsigned short* gA1 = Xb + (size_t)btok[off + sl1] * H_DIM + sgA * 8;
    const int dofsA0 = wv * 512;
    const int dofsA1 = 2048 + wv * 512;

    // B staging: thread -> rows brow, brow+64; natural chunk (tid&3), swizzled write
    const int brow = tid >> 2;                        // 0..63
    const int sgB = (tid & 3) ^ ((tid >> 3) & 3);
    const size_t wrow = (size_t)e * I_DIM + nt * 128 + brow;
    const float* gW1  = W1 + wrow * H_DIM + (tid & 3) * 8;
    const float* gW1b = gW1 + (size_t)64 * H_DIM;
    const float* gW3  = W3 + wrow * H_DIM + (tid & 3) * 8;
    const float* gW3b = gW3 + (size_t)64 * H_DIM;
    const int bwro  = brow * 32 + sgB * 8;
    const int bwro2 = bwro + 2048;

    f32x4 accg[4][4], accu[4][4];
    const f32x4 zero = {0.0f, 0.0f, 0.0f, 0.0f};
    #pragma unroll
    for (int i = 0; i < 4; ++i)
        #pragma unroll
        for (int j = 0; j < 4; ++j) { accg[i][j] = zero; accu[i][j] = zero; }

    float4 w0, w1, w2, w3, w4, w5, w6, w7;

    // ---- prologue: B halves 0,1 direct; A gloads 0,1; prime B(2) regs ----
    #pragma unroll
    for (int h = 0; h < 2; ++h) {
        const float* p1  = gW1  + h * 32;
        const float* p1b = gW1b + h * 32;
        const float* p3  = gW3  + h * 32;
        const float* p3b = gW3b + h * 32;
        *(u16x8*)(&sB1[h][bwro])  = cvt8(((const float4*)p1)[0],  ((const float4*)p1)[1]);
        *(u16x8*)(&sB1[h][bwro2]) = cvt8(((const float4*)p1b)[0], ((const float4*)p1b)[1]);
        *(u16x8*)(&sB3[h][bwro])  = cvt8(((const float4*)p3)[0],  ((const float4*)p3)[1]);
        *(u16x8*)(&sB3[h][bwro2]) = cvt8(((const float4*)p3b)[0], ((const float4*)p3b)[1]);
    }
    async_cp16(gA0,      &sA[0][dofsA0]);
    async_cp16(gA1,      &sA[0][dofsA1]);
    async_cp16(gA0 + 32, &sA[1][dofsA0]);
    async_cp16(gA1 + 32, &sA[1][dofsA1]);
    // B(2) -> regs (consumed at phase 0's write of slot 2)
    w0 = ((const float4*)(gW1  + 64))[0]; w1 = ((const float4*)(gW1  + 64))[1];
    w2 = ((const float4*)(gW1b + 64))[0]; w3 = ((const float4*)(gW1b + 64))[1];
    w4 = ((const float4*)(gW3  + 64))[0]; w5 = ((const float4*)(gW3  + 64))[1];
    w6 = ((const float4*)(gW3b + 64))[0]; w7 = ((const float4*)(gW3b + 64))[1];

    asm volatile("s_waitcnt lgkmcnt(0)" ::: "memory");
    asm volatile("s_waitcnt vmcnt(10)" ::: "memory");   // half 0's A landed
    __builtin_amdgcn_s_barrier();
    __builtin_amdgcn_sched_barrier(0);

    const int NT = H_DIM / 32;   // 64

#define G1_PH(H, S, S2)                                                                              \
    {                                                                                                \
        if ((H) + 2 < NT) {                                                                          \
            *(u16x8*)(&sB1[S2][bwro])  = cvt8(w0, w1);                                               \
            *(u16x8*)(&sB1[S2][bwro2]) = cvt8(w2, w3);                                               \
            *(u16x8*)(&sB3[S2][bwro])  = cvt8(w4, w5);                                               \
            *(u16x8*)(&sB3[S2][bwro2]) = cvt8(w6, w7);                                               \
        }                                                                                            \
        if ((H) + 3 < NT) {                                                                          \
            const float* p1  = gW1  + (size_t)((H) + 3) * 32;                                        \
            const float* p1b = gW1b + (size_t)((H) + 3) * 32;                                        \
            const float* p3  = gW3  + (size_t)((H) + 3) * 32;                                        \
            const float* p3b = gW3b + (size_t)((H) + 3) * 32;                                        \
            w0 = ((const float4*)p1)[0];  w1 = ((const float4*)p1)[1];                               \
            w2 = ((const float4*)p1b)[0]; w3 = ((const float4*)p1b)[1];                              \
            w4 = ((const float4*)p3)[0];  w5 = ((const float4*)p3)[1];                               \
            w6 = ((const float4*)p3b)[0]; w7 = ((const float4*)p3b)[1];                              \
        }                                                                                            \
        bf16x8 af[4], b1f[4], b3f[4];                                                                \
        _Pragma("unroll")                                                                            \
        for (int i = 0; i < 4; ++i) af[i]  = *(const bf16x8*)(&sA[S][aoff + i * 512]);               \
        _Pragma("unroll")                                                                            \
        for (int j = 0; j < 4; ++j) b1f[j] = *(const bf16x8*)(&sB1[S][boff + j * 512]);              \
        _Pragma("unroll")                                                                            \
        for (int j = 0; j < 4; ++j) b3f[j] = *(const bf16x8*)(&sB3[S][boff + j * 512]);              \
        if ((H) + 2 < NT) {                                                                          \
            async_cp16(gA0 + ((H) + 2) * 32, &sA[S2][dofsA0]);                                       \
            async_cp16(gA1 + ((H) + 2) * 32, &sA[S2][dofsA1]);                                       \
        }                                                                                            \
        __builtin_amdgcn_sched_barrier(0);                                                           \
        __builtin_amdgcn_s_setprio(1);                                                               \
        _Pragma("unroll")                                                                            \
        for (int i = 0; i < 4; ++i)                                                                  \
            _Pragma("unroll")                                                                        \
            for (int j = 0; j < 4; ++j)                                                              \
                accg[i][j] = __builtin_amdgcn_mfma_f32_16x16x32_bf16(af[i], b1f[j], accg[i][j], 0, 0, 0); \
        _Pragma("unroll")                                                                            \
        for (int i = 0; i < 4; ++i)                                                                  \
            _Pragma("unroll")                                                                        \
            for (int j = 0; j < 4; ++j)                                                              \
                accu[i][j] = __builtin_amdgcn_mfma_f32_16x16x32_bf16(af[i], b3f[j], accu[i][j], 0, 0, 0); \
        __builtin_amdgcn_s_setprio(0);                                                               \
        if ((H) + 1 < NT) {                                                                          \
            asm volatile("s_waitcnt lgkmcnt(0)" ::: "memory");                                       \
            if ((H) + 3 < NT)      asm volatile("s_waitcnt vmcnt(10)" ::: "memory");                 \
            else if ((H) + 2 < NT) asm volatile("s_waitcnt vmcnt(2)" ::: "memory");                  \
            else                   asm volatile("s_waitcnt vmcnt(0)" ::: "memory");                  \
            __builtin_amdgcn_s_barrier();                                                            \
            __builtin_amdgcn_sched_barrier(0);                                                       \
        }                                                                                            \
    }

    int h = 0;
    for (int t = 0; t < 21; ++t) {       // covers h = 0..62
        G1_PH(h,     0, 2);
        G1_PH(h + 1, 1, 0);
        G1_PH(h + 2, 2, 1);
        h += 3;
    }
    G1_PH(63, 0, 2);                      // 63 % 3 == 0
#undef G1_PH

    // epilogue: silu(gate)*up -> bf16
    #pragma unroll
    for (int i = 0; i < 4; ++i) {
        #pragma unroll
        for (int r = 0; r < 4; ++r) {
            int mloc = wm + i * 16 + q * 4 + r;
            int slot = mt * 128 + mloc;
            if (slot < ne) {
                size_t rowbase = (size_t)(off + slot) * I_DIM + nt * 128 + wn;
                #pragma unroll
                for (int j = 0; j < 4; ++j) {
                    float g = accg[i][j][r];
                    float u = accu[i][j][r];
                    float val = (g / (1.0f + __expf(-g))) * u;
                    hbuf[rowbase + j * 16 + c] = f2bf(val);
                }
            }
        }
    }
}

// GEMM2: out[tok] += wgt * (h[slot] @ W2^T). BM=128 x BN=256, 72KB, 2 blk/CU.
// 32 MFMA/wave/phase (acc[4][8]) — doubles per-phase math density vs BN=128
// (r10 ledger: gemm2p ~700us at 128 phases x 16 MFMA; phase overhead bound).
// Combine fused: exactly 2 commutative fp32 atomicAdds per out element.
__global__ __launch_bounds__(256, 2)
void gemm2p_kernel(const unsigned short* __restrict__ hbuf,
                   const float* __restrict__ W2,
                   const int* __restrict__ counts,
                   const int* __restrict__ offsets,
                   const int* __restrict__ btok,
                   const float* __restrict__ bw,
                   float* __restrict__ out) {
    const int e = blockIdx.z;
    const int ne = counts[e];
    const int mt = blockIdx.y;
    if (mt * 128 >= ne) return;
    const int nt = blockIdx.x;       // H/256 = 8
    const int off = offsets[e];

    __shared__ unsigned short sA[3][128 * 32];   // 24 KB
    __shared__ unsigned short sB[3][256 * 32];   // 48 KB -> 72 KB total

    const int tid = threadIdx.x;
    const int lane = tid & 63;
    const int wv = tid >> 6;
    const int wm = (wv >> 1) << 6;   // {0,64}   (M: 2 waves x 64)
    const int wn = (wv & 1) << 7;    // {0,128}  (N: 2 waves x 128)
    const int q = lane >> 4;
    const int c = lane & 15;
    const int xq = q ^ ((c >> 1) & 3);

    const int aoff = (wm + c) * 32 + xq * 8;
    const int boff = (wn + c) * 32 + xq * 8;

    const int arow = wv * 16 + (lane >> 2);
    const int sgA = (lane & 3) ^ ((lane >> 3) & 3);
    int sl0 = mt * 128 + arow;       if (sl0 >= ne) sl0 = ne - 1;
    int sl1 = mt * 128 + arow + 64;  if (sl1 >= ne) sl1 = ne - 1;
    const unsigned short* gA0 = hbuf + (size_t)(off + sl0) * I_DIM + sgA * 8;
    const unsigned short* gA1 = hbuf + (size_t)(off + sl1) * I_DIM + sgA * 8;
    const int dofsA0 = wv * 512;
    const int dofsA1 = 2048 + wv * 512;

    // B staging: 4 row-groups (brow + {0,64,128,192}); same swizzle per thread
    // ((r>>1)&3 invariant under +64k row offsets).
    const int brow = tid >> 2;
    const int sgB = (tid & 3) ^ ((tid >> 3) & 3);
    const size_t wrow = (size_t)e * H_DIM + nt * 256 + brow;
    const float* gB0 = W2 + wrow * I_DIM + (tid & 3) * 8;
    const float* gB1 = gB0 + (size_t)64  * I_DIM;
    const float* gB2 = gB0 + (size_t)128 * I_DIM;
    const float* gB3 = gB0 + (size_t)192 * I_DIM;
    const int bwro  = brow * 32 + sgB * 8;    // +2048 per 64-row group

    f32x4 acc[4][8];
    const f32x4 zero = {0.0f, 0.0f, 0.0f, 0.0f};
    #pragma unroll
    for (int i = 0; i < 4; ++i)
        #pragma unroll
        for (int j = 0; j < 8; ++j) acc[i][j] = zero;

    float4 w0, w1, w2, w3, w4, w5, w6, w7;

    // ---- prologue: B halves 0,1 direct; A gloads 0,1; prime B(2) regs ----
    #pragma unroll
    for (int h = 0; h < 2; ++h) {
        const float* p0 = gB0 + h * 32;
        const float* p1 = gB1 + h * 32;
        const float* p2 = gB2 + h * 32;
        const float* p3 = gB3 + h * 32;
        *(u16x8*)(&sB[h][bwro])        = cvt8(((const float4*)p0)[0], ((const float4*)p0)[1]);
        *(u16x8*)(&sB[h][bwro + 2048]) = cvt8(((const float4*)p1)[0], ((const float4*)p1)[1]);
        *(u16x8*)(&sB[h][bwro + 4096]) = cvt8(((const float4*)p2)[0], ((const float4*)p2)[1]);
        *(u16x8*)(&sB[h][bwro + 6144]) = cvt8(((const float4*)p3)[0], ((const float4*)p3)[1]);
    }
    async_cp16(gA0,      &sA[0][dofsA0]);
    async_cp16(gA1,      &sA[0][dofsA1]);
    async_cp16(gA0 + 32, &sA[1][dofsA0]);
    async_cp16(gA1 + 32, &sA[1][dofsA1]);
    w0 = ((const float4*)(gB0 + 64))[0]; w1 = ((const float4*)(gB0 + 64))[1];
    w2 = ((const float4*)(gB1 + 64))[0]; w3 = ((const float4*)(gB1 + 64))[1];
    w4 = ((const float4*)(gB2 + 64))[0]; w5 = ((const float4*)(gB2 + 64))[1];
    w6 = ((const float4*)(gB3 + 64))[0]; w7 = ((const float4*)(gB3 + 64))[1];

    asm volatile("s_waitcnt lgkmcnt(0)" ::: "memory");
    asm volatile("s_waitcnt vmcnt(10)" ::: "memory");   // half 0's A landed
    __builtin_amdgcn_s_barrier();
    __builtin_amdgcn_sched_barrier(0);

    const int NT = I_DIM / 32;   // 128

#define G2_PH(H, S, S2)                                                                              \
    {                                                                                                \
        if ((H) + 2 < NT) {                                                                          \
            *(u16x8*)(&sB[S2][bwro])        = cvt8(w0, w1);                                          \
            *(u16x8*)(&sB[S2][bwro + 2048]) = cvt8(w2, w3);                                          \
            *(u16x8*)(&sB[S2][bwro + 4096]) = cvt8(w4, w5);                                          \
            *(u16x8*)(&sB[S2][bwro + 6144]) = cvt8(w6, w7);                                          \
        }                                                                                            \
        if ((H) + 3 < NT) {                                                                          \
            const float* p0 = gB0 + (size_t)((H) + 3) * 32;                                          \
            const float* p1 = gB1 + (size_t)((H) + 3) * 32;                                          \
            const float* p2 = gB2 + (size_t)((H) + 3) * 32;                                          \
            const float* p3 = gB3 + (size_t)((H) + 3) * 32;                                          \
            w0 = ((const float4*)p0)[0]; w1 = ((const float4*)p0)[1];                                \
            w2 = ((const float4*)p1)[0]; w3 = ((const float4*)p1)[1];                                \
            w4 = ((const float4*)p2)[0]; w5 = ((const float4*)p2)[1];                                \
            w6 = ((const float4*)p3)[0]; w7 = ((const float4*)p3)[1];                                \
        }                                                                                            \
        bf16x8 af[4], bfr[8];                                                                        \
        _Pragma("unroll")                                                                            \
        for (int i = 0; i < 4; ++i) af[i]  = *(const bf16x8*)(&sA[S][aoff + i * 512]);               \
        _Pragma("unroll")                                                                            \
        for (int j = 0; j < 8; ++j) bfr[j] = *(const bf16x8*)(&sB[S][boff + j * 512]);               \
        if ((H) + 2 < NT) {                                                                          \
            async_cp16(gA0 + ((H) + 2) * 32, &sA[S2][dofsA0]);                                       \
            async_cp16(gA1 + ((H) + 2) * 32, &sA[S2][dofsA1]);                                       \
        }                                                                                            \
        __builtin_amdgcn_sched_barrier(0);                                                           \
        __builtin_amdgcn_s_setprio(1);                                                               \
        _Pragma("unroll")                                                                            \
        for (int i = 0; i < 4; ++i)                                                                  \
            _Pragma("unroll")                                                                        \
            for (int j = 0; j < 8; ++j)                                                              \
                acc[i][j] = __builtin_amdgcn_mfma_f32_16x16x32_bf16(af[i], bfr[j], acc[i][j], 0, 0, 0); \
        __builtin_amdgcn_s_setprio(0);                                                               \
        if ((H) + 1 < NT) {                                                                          \
            asm volatile("s_waitcnt lgkmcnt(0)" ::: "memory");                                       \
            if ((H) + 3 < NT)      asm volatile("s_waitcnt vmcnt(10)" ::: "memory");                 \
            else if ((H) + 2 < NT) asm volatile("s_waitcnt vmcnt(2)" ::: "memory");                  \
            else                   asm volatile("s_waitcnt vmcnt(0)" ::: "memory");                  \
            __builtin_amdgcn_s_barrier();                                                            \
            __builtin_amdgcn_sched_barrier(0);                                                       \
        }                                                                                            \
    }

    int h = 0;
    for (int t = 0; t < 42; ++t) {       // covers h = 0..125
        G2_PH(h,     0, 2);
        G2_PH(h + 1, 1, 0);
        G2_PH(h + 2, 2, 1);
        h += 3;
    }
    G2_PH(126, 0, 2);                     // 126 % 3 == 0
    G2_PH(127, 1, 0);                     // 127 % 3 == 1
#undef G2_PH

    #pragma unroll
    for (int i = 0; i < 4; ++i) {
        #pragma unroll
        for (int r = 0; r < 4; ++r) {
            int mloc = wm + i * 16 + q * 4 + r;
            int slot = mt * 128 + mloc;
            if (slot < ne) {
                int tok = btok[off + slot];
                float wgt = bw[off + slot];
                float* obase = out + (size_t)tok * H_DIM + nt * 256 + wn;
                #pragma unroll
                for (int j = 0; j < 8; ++j)
                    atomicAdd(obase + j * 16 + c, wgt * acc[i][j][r]);
            }
        }
    }
}

// =====================  PATH B: fallback (fp32 weights in-loop) ==============

__global__ __launch_bounds__(256, 2)
void gemm1_kernel(const unsigned short* __restrict__ Xb,
                  const float* __restrict__ W1,
                  const float* __restrict__ W3,
                  const int* __restrict__ counts,
                  const int* __restrict__ offsets,
                  const int* __restrict__ btok,
                  unsigned short* __restrict__ hbuf) {
    const int e = blockIdx.z;
    const int ne = counts[e];
    const int mt = blockIdx.y;
    if (mt * 128 >= ne) return;
    const int nt = blockIdx.x;
    const int off = offsets[e];

    __shared__ unsigned short sA[128][32];
    __shared__ unsigned short sB1[128][32];
    __shared__ unsigned short sB3[128][32];
    __shared__ int s_tok[128];

    const int tid = threadIdx.x;
    if (tid < 128) {
        int slot = mt * 128 + tid;
        s_tok[tid] = (slot < ne) ? btok[off + slot] : -1;
    }

    const float* __restrict__ pB1 = W1 + (size_t)e * I_DIM * H_DIM + (size_t)(nt * 128) * H_DIM;
    const float* __restrict__ pB3 = W3 + (size_t)e * I_DIM * H_DIM + (size_t)(nt * 128) * H_DIM;

    const int lane = tid & 63;
    const int wv = tid >> 6;
    const int wm = (wv >> 1) << 6;
    const int wn = (wv & 1) << 6;
    const int q = lane >> 4;
    const int c = lane & 15;

    f32x4 accg[4][4], accu[4][4];
    const f32x4 zero = {0.0f, 0.0f, 0.0f, 0.0f};
    #pragma unroll
    for (int i = 0; i < 4; ++i)
        #pragma unroll
        for (int j = 0; j < 4; ++j) { accg[i][j] = zero; accu[i][j] = zero; }

    const int srow = tid >> 2;
    const int schunk = (tid & 3) * 8;

    for (int kt = 0; kt < H_DIM; kt += 32) {
        __syncthreads();
        #pragma unroll
        for (int p = 0; p < 2; ++p) {
            int r = srow + p * 64;
            int tok = s_tok[r];
            u16x8 av = {0, 0, 0, 0, 0, 0, 0, 0};
            if (tok >= 0)
                av = *(const u16x8*)(Xb + (size_t)tok * H_DIM + kt + schunk);
            *(u16x8*)(&sA[r][schunk]) = av;

            const float* b1 = pB1 + (size_t)r * H_DIM + kt + schunk;
            *(u16x8*)(&sB1[r][schunk]) = cvt8(*(const float4*)(b1), *(const float4*)(b1 + 4));

            const float* b3 = pB3 + (size_t)r * H_DIM + kt + schunk;
            *(u16x8*)(&sB3[r][schunk]) = cvt8(*(const float4*)(b3), *(const float4*)(b3 + 4));
        }
        __syncthreads();

        bf16x8 af[4], b1f[4], b3f[4];
        #pragma unroll
        for (int i = 0; i < 4; ++i)
            af[i] = *(const bf16x8*)(&sA[wm + i * 16 + c][q * 8]);
        #pragma unroll
        for (int j = 0; j < 4; ++j) {
            b1f[j] = *(const bf16x8*)(&sB1[wn + j * 16 + c][q * 8]);
            b3f[j] = *(const bf16x8*)(&sB3[wn + j * 16 + c][q * 8]);
        }
        #pragma unroll
        for (int i = 0; i < 4; ++i)
            #pragma unroll
            for (int j = 0; j < 4; ++j) {
                accg[i][j] = __builtin_amdgcn_mfma_f32_16x16x32_bf16(af[i], b1f[j], accg[i][j], 0, 0, 0);
                accu[i][j] = __builtin_amdgcn_mfma_f32_16x16x32_bf16(af[i], b3f[j], accu[i][j], 0, 0, 0);
            }
    }

    #pragma unroll
    for (int i = 0; i < 4; ++i) {
        #pragma unroll
        for (int r = 0; r < 4; ++r) {
            int mloc = wm + i * 16 + q * 4 + r;
            int slot = mt * 128 + mloc;
            if (slot < ne) {
                size_t rowbase = (size_t)(off + slot) * I_DIM + nt * 128 + wn;
                #pragma unroll
                for (int j = 0; j < 4; ++j) {
                    float g = accg[i][j][r];
                    float u = accu[i][j][r];
                    float val = (g / (1.0f + __expf(-g))) * u;
                    hbuf[rowbase + j * 16 + c] = f2bf(val);
                }
            }
        }
    }
}

__global__ __launch_bounds__(256, 2)
void gemm2_kernel(const unsigned short* __restrict__ hbuf,
                  const float* __restrict__ W2,
                  const int* __restrict__ counts,
                  const int* __restrict__ offsets,
                  const int* __restrict__ btok,
                  const float* __restrict__ bw,
                  float* __restrict__ out) {
    const int e = blockIdx.z;
    const int ne = counts[e];
    const int mt = blockIdx.y;
    if (mt * 128 >= ne) return;
    const int nt = blockIdx.x;
    const int off = offsets[e];

    __shared__ unsigned short sA[128][32];
    __shared__ unsigned short sB[128][32];

    const int tid = threadIdx.x;
    const int lane = tid & 63;
    const int wv = tid >> 6;
    const int wm = (wv >> 1) << 6;
    const int wn = (wv & 1) << 6;
    const int q = lane >> 4;
    const int c = lane & 15;

    const float* __restrict__ pB = W2 + (size_t)e * H_DIM * I_DIM + (size_t)(nt * 128) * I_DIM;

    f32x4 acc[4][4];
    const f32x4 zero = {0.0f, 0.0f, 0.0f, 0.0f};
    #pragma unroll
    for (int i = 0; i < 4; ++i)
        #pragma unroll
        for (int j = 0; j < 4; ++j) acc[i][j] = zero;

    const int srow = tid >> 2;
    const int schunk = (tid & 3) * 8;

    for (int kt = 0; kt < I_DIM; kt += 32) {
        __syncthreads();
        #pragma unroll
        for (int p = 0; p < 2; ++p) {
            int r = srow + p * 64;
            int slot = mt * 128 + r;
            u16x8 av = {0, 0, 0, 0, 0, 0, 0, 0};
            if (slot < ne)
                av = *(const u16x8*)(hbuf + (size_t)(off + slot) * I_DIM + kt + schunk);
            *(u16x8*)(&sA[r][schunk]) = av;

            const float* b = pB + (size_t)r * I_DIM + kt + schunk;
            *(u16x8*)(&sB[r][schunk]) = cvt8(*(const float4*)(b), *(const float4*)(b + 4));
        }
        __syncthreads();

        bf16x8 af[4], bfr[4];
        #pragma unroll
        for (int i = 0; i < 4; ++i)
            af[i] = *(const bf16x8*)(&sA[wm + i * 16 + c][q * 8]);
        #pragma unroll
        for (int j = 0; j < 4; ++j)
            bfr[j] = *(const bf16x8*)(&sB[wn + j * 16 + c][q * 8]);
        #pragma unroll
        for (int i = 0; i < 4; ++i)
            #pragma unroll
            for (int j = 0; j < 4; ++j)
                acc[i][j] = __builtin_amdgcn_mfma_f32_16x16x32_bf16(af[i], bfr[j], acc[i][j], 0, 0, 0);
    }

    #pragma unroll
    for (int i = 0; i < 4; ++i) {
        #pragma unroll
        for (int r = 0; r < 4; ++r) {
            int mloc = wm + i * 16 + q * 4 + r;
            int slot = mt * 128 + mloc;
            if (slot < ne) {
                int tok = btok[off + slot];
                float wgt = bw[off + slot];
                float* obase = out + (size_t)tok * H_DIM + nt * 128 + wn;
                #pragma unroll
                for (int j = 0; j < 4; ++j)
                    atomicAdd(obase + j * 16 + c, wgt * acc[i][j][r]);
            }
        }
    }
}

// ============================================================================

extern "C" void kernel_launch(void* const* d_in, const int* in_sizes, int n_in,
                              void* d_out, int out_size, void* d_ws, size_t ws_size,
                              hipStream_t stream) {
    const float* hs = (const float*)d_in[0];   // [T, H]
    const float* rl = (const float*)d_in[1];   // [T, E]
    const float* w1 = (const float*)d_in[2];   // [E, I, H]
    const float* w3 = (const float*)d_in[3];   // [E, I, H]
    const float* w2 = (const float*)d_in[4];   // [E, H, I]
    float* out = (float*)d_out;

    char* ws = (char*)d_ws;
    // meta region (first 1 MB)
    int*   counts   = (int*)(ws);
    int*   offsets  = (int*)(ws + 256);
    int*   btok     = (int*)(ws + 4096);            // 8192 ints
    float* bw       = (float*)(ws + 36864);         // 8192 floats
    int*   tok2slot = (int*)(ws + 69632);           // 8192 ints

    const size_t MB = 1ull << 20;
    const size_t NEED_A = 146 * MB;

    if (ws_size >= NEED_A) {
        // -------- Path A: fused-convert, multi-block/CU GEMMs ---------------
        unsigned short* Xb   = (unsigned short*)(ws + 1 * MB);     // 16 MB
        unsigned short* hbuf = (unsigned short*)(ws + 17 * MB);    // 64 MB

        hipMemsetAsync(out, 0, (size_t)T_TOK * H_DIM * sizeof(float), stream);

        routing_kernel<<<1, 256, 0, stream>>>(rl, counts, offsets, btok, bw, tok2slot);

        cvt_kernel<<<(T_TOK * H_DIM / 8) / 256, 256, 0, stream>>>(hs, Xb);

        gemm1p_kernel<<<dim3(I_DIM / 128, 64, N_EXP), 256, 0, stream>>>(
            Xb, w1, w3, counts, offsets, btok, hbuf);

        gemm2p_kernel<<<dim3(H_DIM / 256, 64, N_EXP), 256, 0, stream>>>(
            hbuf, w2, counts, offsets, btok, bw, out);
    } else {
        // -------- Path B: fallback (known-good round-1 structure) -----------
        unsigned short* Xb   = (unsigned short*)(ws + 1 * MB);            // 16 MB
        unsigned short* hbuf = (unsigned short*)(ws + 32 * MB);           // 64 MB

        hipMemsetAsync(out, 0, (size_t)T_TOK * H_DIM * sizeof(float), stream);

        routing_kernel<<<1, 256, 0, stream>>>(rl, counts, offsets, btok, bw, tok2slot);

        cvt_kernel<<<(T_TOK * H_DIM / 8) / 256, 256, 0, stream>>>(hs, Xb);

        gemm1_kernel<<<dim3(I_DIM / 128, T_TOK / 128, N_EXP), 256, 0, stream>>>(
            Xb, w1, w3, counts, offsets, btok, hbuf);

        gemm2_kernel<<<dim3(H_DIM / 128, T_TOK / 128, N_EXP), 256, 0, stream>>>(
            hbuf, w2, counts, offsets, btok, bw, out);
    }
}

// Round 13
// 1246.338 us; speedup vs baseline: 1.0701x; 1.0701x over previous
//
#include <hip/hip_runtime.h>
#include <stdint.h>

#define T_TOK 4096
#define H_DIM 2048
#define I_DIM 4096
#define N_EXP 8

typedef __attribute__((ext_vector_type(8))) short bf16x8;     // MFMA A/B frag (8 bf16)
typedef __attribute__((ext_vector_type(4))) float f32x4;      // MFMA C/D frag
typedef __attribute__((ext_vector_type(8))) unsigned short u16x8;

// f32->bf16 RNE via integer emulation. NOTE (r7/r9 post-mortem): gfx950's
// v_cvt_pk_bf16_f32 and __builtin_convertvector to __bf16 do NOT match
// numpy's round-to-nearest-even (absmax 0.19-0.31 vs 0.0156) — keep this.
__device__ __forceinline__ unsigned short f2bf(float x) {
    union { float f; unsigned u; } v; v.f = x;
    unsigned r = v.u + 0x7FFF + ((v.u >> 16) & 1);   // RNE
    return (unsigned short)(r >> 16);
}

__device__ __forceinline__ u16x8 cvt8(float4 a, float4 b) {
    u16x8 o;
    o[0] = f2bf(a.x); o[1] = f2bf(a.y); o[2] = f2bf(a.z); o[3] = f2bf(a.w);
    o[4] = f2bf(b.x); o[5] = f2bf(b.y); o[6] = f2bf(b.z); o[7] = f2bf(b.w);
    return o;
}

// Direct global->LDS async copy, 16B per lane. LDS dest = wave-uniform base + lane*16.
__device__ __forceinline__ void async_cp16(const void* g, const unsigned short* lds_base) {
    __builtin_amdgcn_global_load_lds(
        (const __attribute__((address_space(1))) unsigned*)g,
        (__attribute__((address_space(3))) unsigned*)(unsigned)(uintptr_t)lds_base,
        16, 0, 0);
}

// ---------------- routing: top-2 + softmax + bucketize (single block) ----------
__global__ void routing_kernel(const float* __restrict__ logits,
                               int* __restrict__ counts, int* __restrict__ offsets,
                               int* __restrict__ btok, float* __restrict__ bw,
                               int* __restrict__ tok2slot) {
    __shared__ int s_cnt[N_EXP];
    __shared__ int s_off[N_EXP];
    __shared__ int s_cur[N_EXP];
    const int tid = threadIdx.x;   // 256 threads, 16 tokens each
    if (tid < N_EXP) s_cnt[tid] = 0;
    __syncthreads();

    int e0a[16], e1a[16]; float w0a[16], w1a[16];
    #pragma unroll
    for (int it = 0; it < 16; ++it) {
        int t = tid + it * 256;
        float l[8];
        #pragma unroll
        for (int e = 0; e < 8; ++e) l[e] = logits[t * 8 + e];
        int b0 = 0; float v0 = l[0];
        #pragma unroll
        for (int e = 1; e < 8; ++e) if (l[e] > v0) { v0 = l[e]; b0 = e; }
        int b1 = (b0 == 0) ? 1 : 0; float v1 = l[b1];
        #pragma unroll
        for (int e = 0; e < 8; ++e) if (e != b0 && l[e] > v1) { v1 = l[e]; b1 = e; }
        float w0 = 1.0f / (1.0f + __expf(v1 - v0));
        e0a[it] = b0; e1a[it] = b1; w0a[it] = w0; w1a[it] = 1.0f - w0;
        atomicAdd(&s_cnt[b0], 1);
        atomicAdd(&s_cnt[b1], 1);
    }
    __syncthreads();
    if (tid == 0) {
        int acc = 0;
        for (int e = 0; e < N_EXP; ++e) { s_off[e] = acc; s_cur[e] = acc; acc += s_cnt[e]; }
    }
    __syncthreads();
    if (tid < N_EXP) { counts[tid] = s_cnt[tid]; offsets[tid] = s_off[tid]; }
    #pragma unroll
    for (int it = 0; it < 16; ++it) {
        int t = tid + it * 256;
        int p0 = atomicAdd(&s_cur[e0a[it]], 1);
        btok[p0] = t; bw[p0] = w0a[it];
        int p1 = atomicAdd(&s_cur[e1a[it]], 1);
        btok[p1] = t; bw[p1] = w1a[it];
        tok2slot[2 * t] = p0;
        tok2slot[2 * t + 1] = p1;
    }
}

// ---------------- fp32 -> bf16 convert (8 floats / thread) -------------------
__global__ void cvt_kernel(const float* __restrict__ x, unsigned short* __restrict__ xb) {
    int i = blockIdx.x * blockDim.x + threadIdx.x;   // over groups of 8 floats
    float4 a = ((const float4*)x)[2 * i];
    float4 b = ((const float4*)x)[2 * i + 1];
    ((u16x8*)xb)[i] = cvt8(a, b);
}

// =====================  PATH A: fused-convert, multi-block/CU GEMMs ==========
//
// Ring-3 K=32 phase schedule (round-6/10 proven, nt fast for A L2-reuse):
//   phase h: {cvt+ds_write B(h+2) (regs loaded phase h-1) into slot (h+2)%3
//             | reload regs with B(h+3) | ds_read frags (slot h%3)
//             | 2 A gload_lds (h+2) | sched_barrier | setprio(1) MFMA
//             | setprio(0) | lgkmcnt(0) | vmcnt(N) | barrier}
// Invariants:
//   - ds_write at top of phase h targets slot (h+2)%3 == (h-1)%3, whose
//     readers (phase h-1) drained at the previous lgkmcnt(0)+barrier.
//   - vmcnt(N) at end of phase h: only this phase's B-loads + 2 A-gloads
//     remain => A(h+1) landed, B(h+2) regs retired via cvt consumption.
// Swizzle (verified conflict-free): LDS slot p of row r holds global chunk
// p ^ ((r>>1)&3); A via pre-swizzled source + linear gload_lds dest,
// B via natural source chunk + swizzled ds_write; reads at q ^ ((c>>1)&3).

// GEMM1: h[slot,i] = silu(x@W1^T)*(x@W3^T). BM=128 x BN=128, 72KB, 2 blk/CU.
__global__ __launch_bounds__(256, 2)
void gemm1p_kernel(const unsigned short* __restrict__ Xb,
                   const float* __restrict__ W1,
                   const float* __restrict__ W3,
                   const int* __restrict__ counts,
                   const int* __restrict__ offsets,
                   const int* __restrict__ btok,
                   unsigned short* __restrict__ hbuf) {
    const int e = blockIdx.z;
    const int ne = counts[e];
    const int mt = blockIdx.y;
    if (mt * 128 >= ne) return;
    const int nt = blockIdx.x;
    const int off = offsets[e];

    __shared__ unsigned short sA[3][128 * 32];    // 24 KB
    __shared__ unsigned short sB1[3][128 * 32];   // 24 KB
    __shared__ unsigned short sB3[3][128 * 32];   // 24 KB -> 72 KB total

    const int tid = threadIdx.x;
    const int lane = tid & 63;
    const int wv = tid >> 6;         // 0..3
    const int wm = (wv >> 1) << 6;   // {0,64}
    const int wn = (wv & 1) << 6;    // {0,64}
    const int q = lane >> 4;
    const int c = lane & 15;
    const int xq = q ^ ((c >> 1) & 3);          // swizzled read slot

    const int aoff = (wm + c) * 32 + xq * 8;
    const int boff = (wn + c) * 32 + xq * 8;

    // A staging: per wave 16 rows per gload; rows arow and arow+64
    const int arow = wv * 16 + (lane >> 2);           // 0..63
    const int sgA = (lane & 3) ^ ((lane >> 3) & 3);

    int sl0 = mt * 128 + arow;       if (sl0 >= ne) sl0 = ne - 1;
    int sl1 = mt * 128 + arow + 64;  if (sl1 >= ne) sl1 = ne - 1;
    const unsigned short* gA0 = Xb + (size_t)btok[off + sl0] * H_DIM + sgA * 8;
    const unsigned short* gA1 = Xb + (size_t)btok[off + sl1] * H_DIM + sgA * 8;
    const int dofsA0 = wv * 512;
    const int dofsA1 = 2048 + wv * 512;

    // B staging: thread -> rows brow, brow+64; natural chunk (tid&3), swizzled write
    const int brow = tid >> 2;                        // 0..63
    const int sgB = (tid & 3) ^ ((tid >> 3) & 3);
    const size_t wrow = (size_t)e * I_DIM + nt * 128 + brow;
    const float* gW1  = W1 + wrow * H_DIM + (tid & 3) * 8;
    const float* gW1b = gW1 + (size_t)64 * H_DIM;
    const float* gW3  = W3 + wrow * H_DIM + (tid & 3) * 8;
    const float* gW3b = gW3 + (size_t)64 * H_DIM;
    const int bwro  = brow * 32 + sgB * 8;
    const int bwro2 = bwro + 2048;

    f32x4 accg[4][4], accu[4][4];
    const f32x4 zero = {0.0f, 0.0f, 0.0f, 0.0f};
    #pragma unroll
    for (int i = 0; i < 4; ++i)
        #pragma unroll
        for (int j = 0; j < 4; ++j) { accg[i][j] = zero; accu[i][j] = zero; }

    float4 w0, w1, w2, w3, w4, w5, w6, w7;

    // ---- prologue: B halves 0,1 direct; A gloads 0,1; prime B(2) regs ----
    #pragma unroll
    for (int h = 0; h < 2; ++h) {
        const float* p1  = gW1  + h * 32;
        const float* p1b = gW1b + h * 32;
        const float* p3  = gW3  + h * 32;
        const float* p3b = gW3b + h * 32;
        *(u16x8*)(&sB1[h][bwro])  = cvt8(((const float4*)p1)[0],  ((const float4*)p1)[1]);
        *(u16x8*)(&sB1[h][bwro2]) = cvt8(((const float4*)p1b)[0], ((const float4*)p1b)[1]);
        *(u16x8*)(&sB3[h][bwro])  = cvt8(((const float4*)p3)[0],  ((const float4*)p3)[1]);
        *(u16x8*)(&sB3[h][bwro2]) = cvt8(((const float4*)p3b)[0], ((const float4*)p3b)[1]);
    }
    async_cp16(gA0,      &sA[0][dofsA0]);
    async_cp16(gA1,      &sA[0][dofsA1]);
    async_cp16(gA0 + 32, &sA[1][dofsA0]);
    async_cp16(gA1 + 32, &sA[1][dofsA1]);
    // B(2) -> regs (consumed at phase 0's write of slot 2)
    w0 = ((const float4*)(gW1  + 64))[0]; w1 = ((const float4*)(gW1  + 64))[1];
    w2 = ((const float4*)(gW1b + 64))[0]; w3 = ((const float4*)(gW1b + 64))[1];
    w4 = ((const float4*)(gW3  + 64))[0]; w5 = ((const float4*)(gW3  + 64))[1];
    w6 = ((const float4*)(gW3b + 64))[0]; w7 = ((const float4*)(gW3b + 64))[1];

    asm volatile("s_waitcnt lgkmcnt(0)" ::: "memory");
    asm volatile("s_waitcnt vmcnt(10)" ::: "memory");   // half 0's A landed
    __builtin_amdgcn_s_barrier();
    __builtin_amdgcn_sched_barrier(0);

    const int NT = H_DIM / 32;   // 64

#define G1_PH(H, S, S2)                                                                              \
    {                                                                                                \
        if ((H) + 2 < NT) {                                                                          \
            *(u16x8*)(&sB1[S2][bwro])  = cvt8(w0, w1);                                               \
            *(u16x8*)(&sB1[S2][bwro2]) = cvt8(w2, w3);                                               \
            *(u16x8*)(&sB3[S2][bwro])  = cvt8(w4, w5);                                               \
            *(u16x8*)(&sB3[S2][bwro2]) = cvt8(w6, w7);                                               \
        }                                                                                            \
        if ((H) + 3 < NT) {                                                                          \
            const float* p1  = gW1  + (size_t)((H) + 3) * 32;                                        \
            const float* p1b = gW1b + (size_t)((H) + 3) * 32;                                        \
            const float* p3  = gW3  + (size_t)((H) + 3) * 32;                                        \
            const float* p3b = gW3b + (size_t)((H) + 3) * 32;                                        \
            w0 = ((const float4*)p1)[0];  w1 = ((const float4*)p1)[1];                               \
            w2 = ((const float4*)p1b)[0]; w3 = ((const float4*)p1b)[1];                              \
            w4 = ((const float4*)p3)[0];  w5 = ((const float4*)p3)[1];                               \
            w6 = ((const float4*)p3b)[0]; w7 = ((const float4*)p3b)[1];                              \
        }                                                                                            \
        bf16x8 af[4], b1f[4], b3f[4];                                                                \
        _Pragma("unroll")                                                                            \
        for (int i = 0; i < 4; ++i) af[i]  = *(const bf16x8*)(&sA[S][aoff + i * 512]);               \
        _Pragma("unroll")                                                                            \
        for (int j = 0; j < 4; ++j) b1f[j] = *(const bf16x8*)(&sB1[S][boff + j * 512]);              \
        _Pragma("unroll")                                                                            \
        for (int j = 0; j < 4; ++j) b3f[j] = *(const bf16x8*)(&sB3[S][boff + j * 512]);              \
        if ((H) + 2 < NT) {                                                                          \
            async_cp16(gA0 + ((H) + 2) * 32, &sA[S2][dofsA0]);                                       \
            async_cp16(gA1 + ((H) + 2) * 32, &sA[S2][dofsA1]);                                       \
        }                                                                                            \
        __builtin_amdgcn_sched_barrier(0);                                                           \
        __builtin_amdgcn_s_setprio(1);                                                               \
        _Pragma("unroll")                                                                            \
        for (int i = 0; i < 4; ++i)                                                                  \
            _Pragma("unroll")                                                                        \
            for (int j = 0; j < 4; ++j)                                                              \
                accg[i][j] = __builtin_amdgcn_mfma_f32_16x16x32_bf16(af[i], b1f[j], accg[i][j], 0, 0, 0); \
        _Pragma("unroll")                                                                            \
        for (int i = 0; i < 4; ++i)                                                                  \
            _Pragma("unroll")                                                                        \
            for (int j = 0; j < 4; ++j)                                                              \
                accu[i][j] = __builtin_amdgcn_mfma_f32_16x16x32_bf16(af[i], b3f[j], accu[i][j], 0, 0, 0); \
        __builtin_amdgcn_s_setprio(0);                                                               \
        if ((H) + 1 < NT) {                                                                          \
            asm volatile("s_waitcnt lgkmcnt(0)" ::: "memory");                                       \
            if ((H) + 3 < NT)      asm volatile("s_waitcnt vmcnt(10)" ::: "memory");                 \
            else if ((H) + 2 < NT) asm volatile("s_waitcnt vmcnt(2)" ::: "memory");                  \
            else                   asm volatile("s_waitcnt vmcnt(0)" ::: "memory");                  \
            __builtin_amdgcn_s_barrier();                                                            \
            __builtin_amdgcn_sched_barrier(0);                                                       \
        }                                                                                            \
    }

    int h = 0;
    for (int t = 0; t < 21; ++t) {       // covers h = 0..62
        G1_PH(h,     0, 2);
        G1_PH(h + 1, 1, 0);
        G1_PH(h + 2, 2, 1);
        h += 3;
    }
    G1_PH(63, 0, 2);                      // 63 % 3 == 0
#undef G1_PH

    // epilogue: silu(gate)*up -> bf16
    #pragma unroll
    for (int i = 0; i < 4; ++i) {
        #pragma unroll
        for (int r = 0; r < 4; ++r) {
            int mloc = wm + i * 16 + q * 4 + r;
            int slot = mt * 128 + mloc;
            if (slot < ne) {
                size_t rowbase = (size_t)(off + slot) * I_DIM + nt * 128 + wn;
                #pragma unroll
                for (int j = 0; j < 4; ++j) {
                    float g = accg[i][j][r];
                    float u = accu[i][j][r];
                    float val = (g / (1.0f + __expf(-g))) * u;
                    hbuf[rowbase + j * 16 + c] = f2bf(val);
                }
            }
        }
    }
}

// GEMM2: out[tok] += wgt * (h[slot] @ W2^T). BM=128 x BN=128, 48KB, 3 blk/CU.
// Combine fused: exactly 2 commutative fp32 atomicAdds per out element;
// out is zeroed by the launcher's memset (replay-safe: memset is in-graph).
__global__ __launch_bounds__(256, 3)
void gemm2p_kernel(const unsigned short* __restrict__ hbuf,
                   const float* __restrict__ W2,
                   const int* __restrict__ counts,
                   const int* __restrict__ offsets,
                   const int* __restrict__ btok,
                   const float* __restrict__ bw,
                   float* __restrict__ out) {
    const int e = blockIdx.z;
    const int ne = counts[e];
    const int mt = blockIdx.y;
    if (mt * 128 >= ne) return;
    const int nt = blockIdx.x;
    const int off = offsets[e];

    __shared__ unsigned short sA[3][128 * 32];   // 24 KB
    __shared__ unsigned short sB[3][128 * 32];   // 24 KB -> 48 KB total

    const int tid = threadIdx.x;
    const int lane = tid & 63;
    const int wv = tid >> 6;
    const int wm = (wv >> 1) << 6;
    const int wn = (wv & 1) << 6;
    const int q = lane >> 4;
    const int c = lane & 15;
    const int xq = q ^ ((c >> 1) & 3);

    const int aoff = (wm + c) * 32 + xq * 8;
    const int boff = (wn + c) * 32 + xq * 8;

    const int arow = wv * 16 + (lane >> 2);
    const int sgA = (lane & 3) ^ ((lane >> 3) & 3);
    int sl0 = mt * 128 + arow;       if (sl0 >= ne) sl0 = ne - 1;
    int sl1 = mt * 128 + arow + 64;  if (sl1 >= ne) sl1 = ne - 1;
    const unsigned short* gA0 = hbuf + (size_t)(off + sl0) * I_DIM + sgA * 8;
    const unsigned short* gA1 = hbuf + (size_t)(off + sl1) * I_DIM + sgA * 8;
    const int dofsA0 = wv * 512;
    const int dofsA1 = 2048 + wv * 512;

    const int brow = tid >> 2;
    const int sgB = (tid & 3) ^ ((tid >> 3) & 3);
    const size_t wrow = (size_t)e * H_DIM + nt * 128 + brow;
    const float* gB  = W2 + wrow * I_DIM + (tid & 3) * 8;
    const float* gBb = gB + (size_t)64 * I_DIM;
    const int bwro  = brow * 32 + sgB * 8;
    const int bwro2 = bwro + 2048;

    f32x4 acc[4][4];
    const f32x4 zero = {0.0f, 0.0f, 0.0f, 0.0f};
    #pragma unroll
    for (int i = 0; i < 4; ++i)
        #pragma unroll
        for (int j = 0; j < 4; ++j) acc[i][j] = zero;

    float4 w0, w1, w2, w3;

    // ---- prologue ----
    #pragma unroll
    for (int h = 0; h < 2; ++h) {
        const float* p  = gB  + h * 32;
        const float* pb = gBb + h * 32;
        *(u16x8*)(&sB[h][bwro])  = cvt8(((const float4*)p)[0],  ((const float4*)p)[1]);
        *(u16x8*)(&sB[h][bwro2]) = cvt8(((const float4*)pb)[0], ((const float4*)pb)[1]);
    }
    async_cp16(gA0,      &sA[0][dofsA0]);
    async_cp16(gA1,      &sA[0][dofsA1]);
    async_cp16(gA0 + 32, &sA[1][dofsA0]);
    async_cp16(gA1 + 32, &sA[1][dofsA1]);
    w0 = ((const float4*)(gB  + 64))[0]; w1 = ((const float4*)(gB  + 64))[1];
    w2 = ((const float4*)(gBb + 64))[0]; w3 = ((const float4*)(gBb + 64))[1];

    asm volatile("s_waitcnt lgkmcnt(0)" ::: "memory");
    asm volatile("s_waitcnt vmcnt(6)" ::: "memory");
    __builtin_amdgcn_s_barrier();
    __builtin_amdgcn_sched_barrier(0);

    const int NT = I_DIM / 32;   // 128

#define G2_PH(H, S, S2)                                                                              \
    {                                                                                                \
        if ((H) + 2 < NT) {                                                                          \
            *(u16x8*)(&sB[S2][bwro])  = cvt8(w0, w1);                                                \
            *(u16x8*)(&sB[S2][bwro2]) = cvt8(w2, w3);                                                \
        }                                                                                            \
        if ((H) + 3 < NT) {                                                                          \
            const float* p  = gB  + (size_t)((H) + 3) * 32;                                          \
            const float* pb = gBb + (size_t)((H) + 3) * 32;                                          \
            w0 = ((const float4*)p)[0];  w1 = ((const float4*)p)[1];                                 \
            w2 = ((const float4*)pb)[0]; w3 = ((const float4*)pb)[1];                                \
        }                                                                                            \
        bf16x8 af[4], bfr[4];                                                                        \
        _Pragma("unroll")                                                                            \
        for (int i = 0; i < 4; ++i) af[i]  = *(const bf16x8*)(&sA[S][aoff + i * 512]);               \
        _Pragma("unroll")                                                                            \
        for (int j = 0; j < 4; ++j) bfr[j] = *(const bf16x8*)(&sB[S][boff + j * 512]);               \
        if ((H) + 2 < NT) {                                                                          \
            async_cp16(gA0 + ((H) + 2) * 32, &sA[S2][dofsA0]);                                       \
            async_cp16(gA1 + ((H) + 2) * 32, &sA[S2][dofsA1]);                                       \
        }                                                                                            \
        __builtin_amdgcn_sched_barrier(0);                                                           \
        __builtin_amdgcn_s_setprio(1);                                                               \
        _Pragma("unroll")                                                                            \
        for (int i = 0; i < 4; ++i)                                                                  \
            _Pragma("unroll")                                                                        \
            for (int j = 0; j < 4; ++j)                                                              \
                acc[i][j] = __builtin_amdgcn_mfma_f32_16x16x32_bf16(af[i], bfr[j], acc[i][j], 0, 0, 0); \
        __builtin_amdgcn_s_setprio(0);                                                               \
        if ((H) + 1 < NT) {                                                                          \
            asm volatile("s_waitcnt lgkmcnt(0)" ::: "memory");                                       \
            if ((H) + 3 < NT)      asm volatile("s_waitcnt vmcnt(6)" ::: "memory");                  \
            else if ((H) + 2 < NT) asm volatile("s_waitcnt vmcnt(2)" ::: "memory");                  \
            else                   asm volatile("s_waitcnt vmcnt(0)" ::: "memory");                  \
            __builtin_amdgcn_s_barrier();                                                            \
            __builtin_amdgcn_sched_barrier(0);                                                       \
        }                                                                                            \
    }

    int h = 0;
    for (int t = 0; t < 42; ++t) {       // covers h = 0..125
        G2_PH(h,     0, 2);
        G2_PH(h + 1, 1, 0);
        G2_PH(h + 2, 2, 1);
        h += 3;
    }
    G2_PH(126, 0, 2);                     // 126 % 3 == 0
    G2_PH(127, 1, 0);                     // 127 % 3 == 1
#undef G2_PH

    #pragma unroll
    for (int i = 0; i < 4; ++i) {
        #pragma unroll
        for (int r = 0; r < 4; ++r) {
            int mloc = wm + i * 16 + q * 4 + r;
            int slot = mt * 128 + mloc;
            if (slot < ne) {
                int tok = btok[off + slot];
                float wgt = bw[off + slot];
                float* obase = out + (size_t)tok * H_DIM + nt * 128 + wn;
                #pragma unroll
                for (int j = 0; j < 4; ++j)
                    atomicAdd(obase + j * 16 + c, wgt * acc[i][j][r]);
            }
        }
    }
}

// =====================  PATH B: fallback (fp32 weights in-loop) ==============

__global__ __launch_bounds__(256, 2)
void gemm1_kernel(const unsigned short* __restrict__ Xb,
                  const float* __restrict__ W1,
                  const float* __restrict__ W3,
                  const int* __restrict__ counts,
                  const int* __restrict__ offsets,
                  const int* __restrict__ btok,
                  unsigned short* __restrict__ hbuf) {
    const int e = blockIdx.z;
    const int ne = counts[e];
    const int mt = blockIdx.y;
    if (mt * 128 >= ne) return;
    const int nt = blockIdx.x;
    const int off = offsets[e];

    __shared__ unsigned short sA[128][32];
    __shared__ unsigned short sB1[128][32];
    __shared__ unsigned short sB3[128][32];
    __shared__ int s_tok[128];

    const int tid = threadIdx.x;
    if (tid < 128) {
        int slot = mt * 128 + tid;
        s_tok[tid] = (slot < ne) ? btok[off + slot] : -1;
    }

    const float* __restrict__ pB1 = W1 + (size_t)e * I_DIM * H_DIM + (size_t)(nt * 128) * H_DIM;
    const float* __restrict__ pB3 = W3 + (size_t)e * I_DIM * H_DIM + (size_t)(nt * 128) * H_DIM;

    const int lane = tid & 63;
    const int wv = tid >> 6;
    const int wm = (wv >> 1) << 6;
    const int wn = (wv & 1) << 6;
    const int q = lane >> 4;
    const int c = lane & 15;

    f32x4 accg[4][4], accu[4][4];
    const f32x4 zero = {0.0f, 0.0f, 0.0f, 0.0f};
    #pragma unroll
    for (int i = 0; i < 4; ++i)
        #pragma unroll
        for (int j = 0; j < 4; ++j) { accg[i][j] = zero; accu[i][j] = zero; }

    const int srow = tid >> 2;
    const int schunk = (tid & 3) * 8;

    for (int kt = 0; kt < H_DIM; kt += 32) {
        __syncthreads();
        #pragma unroll
        for (int p = 0; p < 2; ++p) {
            int r = srow + p * 64;
            int tok = s_tok[r];
            u16x8 av = {0, 0, 0, 0, 0, 0, 0, 0};
            if (tok >= 0)
                av = *(const u16x8*)(Xb + (size_t)tok * H_DIM + kt + schunk);
            *(u16x8*)(&sA[r][schunk]) = av;

            const float* b1 = pB1 + (size_t)r * H_DIM + kt + schunk;
            *(u16x8*)(&sB1[r][schunk]) = cvt8(*(const float4*)(b1), *(const float4*)(b1 + 4));

            const float* b3 = pB3 + (size_t)r * H_DIM + kt + schunk;
            *(u16x8*)(&sB3[r][schunk]) = cvt8(*(const float4*)(b3), *(const float4*)(b3 + 4));
        }
        __syncthreads();

        bf16x8 af[4], b1f[4], b3f[4];
        #pragma unroll
        for (int i = 0; i < 4; ++i)
            af[i] = *(const bf16x8*)(&sA[wm + i * 16 + c][q * 8]);
        #pragma unroll
        for (int j = 0; j < 4; ++j) {
            b1f[j] = *(const bf16x8*)(&sB1[wn + j * 16 + c][q * 8]);
            b3f[j] = *(const bf16x8*)(&sB3[wn + j * 16 + c][q * 8]);
        }
        #pragma unroll
        for (int i = 0; i < 4; ++i)
            #pragma unroll
            for (int j = 0; j < 4; ++j) {
                accg[i][j] = __builtin_amdgcn_mfma_f32_16x16x32_bf16(af[i], b1f[j], accg[i][j], 0, 0, 0);
                accu[i][j] = __builtin_amdgcn_mfma_f32_16x16x32_bf16(af[i], b3f[j], accu[i][j], 0, 0, 0);
            }
    }

    #pragma unroll
    for (int i = 0; i < 4; ++i) {
        #pragma unroll
        for (int r = 0; r < 4; ++r) {
            int mloc = wm + i * 16 + q * 4 + r;
            int slot = mt * 128 + mloc;
            if (slot < ne) {
                size_t rowbase = (size_t)(off + slot) * I_DIM + nt * 128 + wn;
                #pragma unroll
                for (int j = 0; j < 4; ++j) {
                    float g = accg[i][j][r];
                    float u = accu[i][j][r];
                    float val = (g / (1.0f + __expf(-g))) * u;
                    hbuf[rowbase + j * 16 + c] = f2bf(val);
                }
            }
        }
    }
}

__global__ __launch_bounds__(256, 2)
void gemm2_kernel(const unsigned short* __restrict__ hbuf,
                  const float* __restrict__ W2,
                  const int* __restrict__ counts,
                  const int* __restrict__ offsets,
                  const int* __restrict__ btok,
                  const float* __restrict__ bw,
                  float* __restrict__ out) {
    const int e = blockIdx.z;
    const int ne = counts[e];
    const int mt = blockIdx.y;
    if (mt * 128 >= ne) return;
    const int nt = blockIdx.x;
    const int off = offsets[e];

    __shared__ unsigned short sA[128][32];
    __shared__ unsigned short sB[128][32];

    const int tid = threadIdx.x;
    const int lane = tid & 63;
    const int wv = tid >> 6;
    const int wm = (wv >> 1) << 6;
    const int wn = (wv & 1) << 6;
    const int q = lane >> 4;
    const int c = lane & 15;

    const float* __restrict__ pB = W2 + (size_t)e * H_DIM * I_DIM + (size_t)(nt * 128) * I_DIM;

    f32x4 acc[4][4];
    const f32x4 zero = {0.0f, 0.0f, 0.0f, 0.0f};
    #pragma unroll
    for (int i = 0; i < 4; ++i)
        #pragma unroll
        for (int j = 0; j < 4; ++j) acc[i][j] = zero;

    const int srow = tid >> 2;
    const int schunk = (tid & 3) * 8;

    for (int kt = 0; kt < I_DIM; kt += 32) {
        __syncthreads();
        #pragma unroll
        for (int p = 0; p < 2; ++p) {
            int r = srow + p * 64;
            int slot = mt * 128 + r;
            u16x8 av = {0, 0, 0, 0, 0, 0, 0, 0};
            if (slot < ne)
                av = *(const u16x8*)(hbuf + (size_t)(off + slot) * I_DIM + kt + schunk);
            *(u16x8*)(&sA[r][schunk]) = av;

            const float* b = pB + (size_t)r * I_DIM + kt + schunk;
            *(u16x8*)(&sB[r][schunk]) = cvt8(*(const float4*)(b), *(const float4*)(b + 4));
        }
        __syncthreads();

        bf16x8 af[4], bfr[4];
        #pragma unroll
        for (int i = 0; i < 4; ++i)
            af[i] = *(const bf16x8*)(&sA[wm + i * 16 + c][q * 8]);
        #pragma unroll
        for (int j = 0; j < 4; ++j)
            bfr[j] = *(const bf16x8*)(&sB[wn + j * 16 + c][q * 8]);
        #pragma unroll
        for (int i = 0; i < 4; ++i)
            #pragma unroll
            for (int j = 0; j < 4; ++j)
                acc[i][j] = __builtin_amdgcn_mfma_f32_16x16x32_bf16(af[i], bfr[j], acc[i][j], 0, 0, 0);
    }

    #pragma unroll
    for (int i = 0; i < 4; ++i) {
        #pragma unroll
        for (int r = 0; r < 4; ++r) {
            int mloc = wm + i * 16 + q * 4 + r;
            int slot = mt * 128 + mloc;
            if (slot < ne) {
                int tok = btok[off + slot];
                float wgt = bw[off + slot];
                float* obase = out + (size_t)tok * H_DIM + nt * 128 + wn;
                #pragma unroll
                for (int j = 0; j < 4; ++j)
                    atomicAdd(obase + j * 16 + c, wgt * acc[i][j][r]);
            }
        }
    }
}

// ============================================================================

extern "C" void kernel_launch(void* const* d_in, const int* in_sizes, int n_in,
                              void* d_out, int out_size, void* d_ws, size_t ws_size,
                              hipStream_t stream) {
    const float* hs = (const float*)d_in[0];   // [T, H]
    const float* rl = (const float*)d_in[1];   // [T, E]
    const float* w1 = (const float*)d_in[2];   // [E, I, H]
    const float* w3 = (const float*)d_in[3];   // [E, I, H]
    const float* w2 = (const float*)d_in[4];   // [E, H, I]
    float* out = (float*)d_out;

    char* ws = (char*)d_ws;
    // meta region (first 1 MB)
    int*   counts   = (int*)(ws);
    int*   offsets  = (int*)(ws + 256);
    int*   btok     = (int*)(ws + 4096);            // 8192 ints
    float* bw       = (float*)(ws + 36864);         // 8192 floats
    int*   tok2slot = (int*)(ws + 69632);           // 8192 ints

    const size_t MB = 1ull << 20;
    const size_t NEED_A = 146 * MB;

    if (ws_size >= NEED_A) {
        // -------- Path A: fused-convert, multi-block/CU GEMMs ---------------
        unsigned short* Xb   = (unsigned short*)(ws + 1 * MB);     // 16 MB
        unsigned short* hbuf = (unsigned short*)(ws + 17 * MB);    // 64 MB

        hipMemsetAsync(out, 0, (size_t)T_TOK * H_DIM * sizeof(float), stream);

        routing_kernel<<<1, 256, 0, stream>>>(rl, counts, offsets, btok, bw, tok2slot);

        cvt_kernel<<<(T_TOK * H_DIM / 8) / 256, 256, 0, stream>>>(hs, Xb);

        gemm1p_kernel<<<dim3(I_DIM / 128, 64, N_EXP), 256, 0, stream>>>(
            Xb, w1, w3, counts, offsets, btok, hbuf);

        gemm2p_kernel<<<dim3(H_DIM / 128, 64, N_EXP), 256, 0, stream>>>(
            hbuf, w2, counts, offsets, btok, bw, out);
    } else {
        // -------- Path B: fallback (known-good round-1 structure) -----------
        unsigned short* Xb   = (unsigned short*)(ws + 1 * MB);            // 16 MB
        unsigned short* hbuf = (unsigned short*)(ws + 32 * MB);           // 64 MB

        hipMemsetAsync(out, 0, (size_t)T_TOK * H_DIM * sizeof(float), stream);

        routing_kernel<<<1, 256, 0, stream>>>(rl, counts, offsets, btok, bw, tok2slot);

        cvt_kernel<<<(T_TOK * H_DIM / 8) / 256, 256, 0, stream>>>(hs, Xb);

        gemm1_kernel<<<dim3(I_DIM / 128, T_TOK / 128, N_EXP), 256, 0, stream>>>(
            Xb, w1, w3, counts, offsets, btok, hbuf);

        gemm2_kernel<<<dim3(H_DIM / 128, T_TOK / 128, N_EXP), 256, 0, stream>>>(
            hbuf, w2, counts, offsets, btok, bw, out);
    }
}

// Round 14
// 1242.885 us; speedup vs baseline: 1.0731x; 1.0028x over previous
//
#include <hip/hip_runtime.h>
#include <stdint.h>

#define T_TOK 4096
#define H_DIM 2048
#define I_DIM 4096
#define N_EXP 8

typedef __attribute__((ext_vector_type(8))) short bf16x8;     // MFMA A/B frag (8 bf16)
typedef __attribute__((ext_vector_type(4))) float f32x4;      // MFMA C/D frag
typedef __attribute__((ext_vector_type(8))) unsigned short u16x8;
typedef __attribute__((ext_vector_type(4))) unsigned int u32x4;

// f32->bf16 RNE via integer emulation. NOTE (r7/r9 post-mortem): gfx950's
// v_cvt_pk_bf16_f32 and __builtin_convertvector to __bf16 do NOT match
// numpy's round-to-nearest-even (absmax 0.19-0.31 vs 0.0156) — keep this.
__device__ __forceinline__ unsigned short f2bf(float x) {
    union { float f; unsigned u; } v; v.f = x;
    unsigned r = v.u + 0x7FFF + ((v.u >> 16) & 1);   // RNE
    return (unsigned short)(r >> 16);
}

// Rounded 32-bit value whose high half is the bf16 (same integer RNE).
__device__ __forceinline__ unsigned rnd32(float x) {
    union { float f; unsigned u; } v; v.f = x;
    return v.u + 0x7FFF + ((v.u >> 16) & 1);   // bfe + add3 (2 VALU)
}

// Pack two bf16 (high halves of ra/rb) into one u32 with v_perm_b32:
// sel 0x07060302 -> out = [ra.b3 ra.b2 rb.b3 rb.b2] = hi16(ra)<<16 | hi16(rb).
// Bit-identical to the previous shift/truncate chain, ~half the VALU ops.
__device__ __forceinline__ unsigned pack2(unsigned hi, unsigned lo) {
    return __builtin_amdgcn_perm(hi, lo, 0x07060302u);
}

__device__ __forceinline__ u16x8 cvt8(float4 a, float4 b) {
    union { u32x4 w; u16x8 u; } r;
    r.w[0] = pack2(rnd32(a.y), rnd32(a.x));   // lo16 = bf16(a.x), hi16 = bf16(a.y)
    r.w[1] = pack2(rnd32(a.w), rnd32(a.z));
    r.w[2] = pack2(rnd32(b.y), rnd32(b.x));
    r.w[3] = pack2(rnd32(b.w), rnd32(b.z));
    return r.u;
}

// Direct global->LDS async copy, 16B per lane. LDS dest = wave-uniform base + lane*16.
__device__ __forceinline__ void async_cp16(const void* g, const unsigned short* lds_base) {
    __builtin_amdgcn_global_load_lds(
        (const __attribute__((address_space(1))) unsigned*)g,
        (__attribute__((address_space(3))) unsigned*)(unsigned)(uintptr_t)lds_base,
        16, 0, 0);
}

// ---------------- routing: top-2 + softmax + bucketize (single block) ----------
__global__ void routing_kernel(const float* __restrict__ logits,
                               int* __restrict__ counts, int* __restrict__ offsets,
                               int* __restrict__ btok, float* __restrict__ bw,
                               int* __restrict__ tok2slot) {
    __shared__ int s_cnt[N_EXP];
    __shared__ int s_off[N_EXP];
    __shared__ int s_cur[N_EXP];
    const int tid = threadIdx.x;   // 256 threads, 16 tokens each
    if (tid < N_EXP) s_cnt[tid] = 0;
    __syncthreads();

    int e0a[16], e1a[16]; float w0a[16], w1a[16];
    #pragma unroll
    for (int it = 0; it < 16; ++it) {
        int t = tid + it * 256;
        float l[8];
        #pragma unroll
        for (int e = 0; e < 8; ++e) l[e] = logits[t * 8 + e];
        int b0 = 0; float v0 = l[0];
        #pragma unroll
        for (int e = 1; e < 8; ++e) if (l[e] > v0) { v0 = l[e]; b0 = e; }
        int b1 = (b0 == 0) ? 1 : 0; float v1 = l[b1];
        #pragma unroll
        for (int e = 0; e < 8; ++e) if (e != b0 && l[e] > v1) { v1 = l[e]; b1 = e; }
        float w0 = 1.0f / (1.0f + __expf(v1 - v0));
        e0a[it] = b0; e1a[it] = b1; w0a[it] = w0; w1a[it] = 1.0f - w0;
        atomicAdd(&s_cnt[b0], 1);
        atomicAdd(&s_cnt[b1], 1);
    }
    __syncthreads();
    if (tid == 0) {
        int acc = 0;
        for (int e = 0; e < N_EXP; ++e) { s_off[e] = acc; s_cur[e] = acc; acc += s_cnt[e]; }
    }
    __syncthreads();
    if (tid < N_EXP) { counts[tid] = s_cnt[tid]; offsets[tid] = s_off[tid]; }
    #pragma unroll
    for (int it = 0; it < 16; ++it) {
        int t = tid + it * 256;
        int p0 = atomicAdd(&s_cur[e0a[it]], 1);
        btok[p0] = t; bw[p0] = w0a[it];
        int p1 = atomicAdd(&s_cur[e1a[it]], 1);
        btok[p1] = t; bw[p1] = w1a[it];
        tok2slot[2 * t] = p0;
        tok2slot[2 * t + 1] = p1;
    }
}

// ---------------- fp32 -> bf16 convert (8 floats / thread) -------------------
__global__ void cvt_kernel(const float* __restrict__ x, unsigned short* __restrict__ xb) {
    int i = blockIdx.x * blockDim.x + threadIdx.x;   // over groups of 8 floats
    float4 a = ((const float4*)x)[2 * i];
    float4 b = ((const float4*)x)[2 * i + 1];
    ((u16x8*)xb)[i] = cvt8(a, b);
}

// =====================  PATH A: fused-convert, multi-block/CU GEMMs ==========
//
// Ring-3 K=32 phase schedule (round-6/10 proven, nt fast for A L2-reuse):
//   phase h: {cvt+ds_write B(h+2) (regs loaded phase h-1) into slot (h+2)%3
//             | reload regs with B(h+3) | ds_read frags (slot h%3)
//             | 2 A gload_lds (h+2) | sched_barrier | setprio(1) MFMA
//             | setprio(0) | lgkmcnt(0) | vmcnt(N) | barrier}
// Invariants:
//   - ds_write at top of phase h targets slot (h+2)%3 == (h-1)%3, whose
//     readers (phase h-1) drained at the previous lgkmcnt(0)+barrier.
//   - vmcnt(N) at end of phase h: only this phase's B-loads + 2 A-gloads
//     remain => A(h+1) landed, B(h+2) regs retired via cvt consumption.
// Swizzle (verified conflict-free): LDS slot p of row r holds global chunk
// p ^ ((r>>1)&3); A via pre-swizzled source + linear gload_lds dest,
// B via natural source chunk + swizzled ds_write; reads at q ^ ((c>>1)&3).

// GEMM1: h[slot,i] = silu(x@W1^T)*(x@W3^T). BM=128 x BN=128, 72KB, 2 blk/CU.
__global__ __launch_bounds__(256, 2)
void gemm1p_kernel(const unsigned short* __restrict__ Xb,
                   const float* __restrict__ W1,
                   const float* __restrict__ W3,
                   const int* __restrict__ counts,
                   const int* __restrict__ offsets,
                   const int* __restrict__ btok,
                   unsigned short* __restrict__ hbuf) {
    const int e = blockIdx.z;
    const int ne = counts[e];
    const int mt = blockIdx.y;
    if (mt * 128 >= ne) return;
    const int nt = blockIdx.x;
    const int off = offsets[e];

    __shared__ unsigned short sA[3][128 * 32];    // 24 KB
    __shared__ unsigned short sB1[3][128 * 32];   // 24 KB
    __shared__ unsigned short sB3[3][128 * 32];   // 24 KB -> 72 KB total

    const int tid = threadIdx.x;
    const int lane = tid & 63;
    const int wv = tid >> 6;         // 0..3
    const int wm = (wv >> 1) << 6;   // {0,64}
    const int wn = (wv & 1) << 6;    // {0,64}
    const int q = lane >> 4;
    const int c = lane & 15;
    const int xq = q ^ ((c >> 1) & 3);          // swizzled read slot

    const int aoff = (wm + c) * 32 + xq * 8;
    const int boff = (wn + c) * 32 + xq * 8;

    // A staging: per wave 16 rows per gload; rows arow and arow+64
    const int arow = wv * 16 + (lane >> 2);           // 0..63
    const int sgA = (lane & 3) ^ ((lane >> 3) & 3);

    int sl0 = mt * 128 + arow;       if (sl0 >= ne) sl0 = ne - 1;
    int sl1 = mt * 128 + arow + 64;  if (sl1 >= ne) sl1 = ne - 1;
    const unsigned short* gA0 = Xb + (size_t)btok[off + sl0] * H_DIM + sgA * 8;
    const unsigned short* gA1 = Xb + (size_t)btok[off + sl1] * H_DIM + sgA * 8;
    const int dofsA0 = wv * 512;
    const int dofsA1 = 2048 + wv * 512;

    // B staging: thread -> rows brow, brow+64; natural chunk (tid&3), swizzled write
    const int brow = tid >> 2;                        // 0..63
    const int sgB = (tid & 3) ^ ((tid >> 3) & 3);
    const size_t wrow = (size_t)e * I_DIM + nt * 128 + brow;
    const float* gW1  = W1 + wrow * H_DIM + (tid & 3) * 8;
    const float* gW1b = gW1 + (size_t)64 * H_DIM;
    const float* gW3  = W3 + wrow * H_DIM + (tid & 3) * 8;
    const float* gW3b = gW3 + (size_t)64 * H_DIM;
    const int bwro  = brow * 32 + sgB * 8;
    const int bwro2 = bwro + 2048;

    f32x4 accg[4][4], accu[4][4];
    const f32x4 zero = {0.0f, 0.0f, 0.0f, 0.0f};
    #pragma unroll
    for (int i = 0; i < 4; ++i)
        #pragma unroll
        for (int j = 0; j < 4; ++j) { accg[i][j] = zero; accu[i][j] = zero; }

    float4 w0, w1, w2, w3, w4, w5, w6, w7;

    // ---- prologue: B halves 0,1 direct; A gloads 0,1; prime B(2) regs ----
    #pragma unroll
    for (int h = 0; h < 2; ++h) {
        const float* p1  = gW1  + h * 32;
        const float* p1b = gW1b + h * 32;
        const float* p3  = gW3  + h * 32;
        const float* p3b = gW3b + h * 32;
        *(u16x8*)(&sB1[h][bwro])  = cvt8(((const float4*)p1)[0],  ((const float4*)p1)[1]);
        *(u16x8*)(&sB1[h][bwro2]) = cvt8(((const float4*)p1b)[0], ((const float4*)p1b)[1]);
        *(u16x8*)(&sB3[h][bwro])  = cvt8(((const float4*)p3)[0],  ((const float4*)p3)[1]);
        *(u16x8*)(&sB3[h][bwro2]) = cvt8(((const float4*)p3b)[0], ((const float4*)p3b)[1]);
    }
    async_cp16(gA0,      &sA[0][dofsA0]);
    async_cp16(gA1,      &sA[0][dofsA1]);
    async_cp16(gA0 + 32, &sA[1][dofsA0]);
    async_cp16(gA1 + 32, &sA[1][dofsA1]);
    // B(2) -> regs (consumed at phase 0's write of slot 2)
    w0 = ((const float4*)(gW1  + 64))[0]; w1 = ((const float4*)(gW1  + 64))[1];
    w2 = ((const float4*)(gW1b + 64))[0]; w3 = ((const float4*)(gW1b + 64))[1];
    w4 = ((const float4*)(gW3  + 64))[0]; w5 = ((const float4*)(gW3  + 64))[1];
    w6 = ((const float4*)(gW3b + 64))[0]; w7 = ((const float4*)(gW3b + 64))[1];

    asm volatile("s_waitcnt lgkmcnt(0)" ::: "memory");
    asm volatile("s_waitcnt vmcnt(10)" ::: "memory");   // half 0's A landed
    __builtin_amdgcn_s_barrier();
    __builtin_amdgcn_sched_barrier(0);

    const int NT = H_DIM / 32;   // 64

#define G1_PH(H, S, S2)                                                                              \
    {                                                                                                \
        if ((H) + 2 < NT) {                                                                          \
            *(u16x8*)(&sB1[S2][bwro])  = cvt8(w0, w1);                                               \
            *(u16x8*)(&sB1[S2][bwro2]) = cvt8(w2, w3);                                               \
            *(u16x8*)(&sB3[S2][bwro])  = cvt8(w4, w5);                                               \
            *(u16x8*)(&sB3[S2][bwro2]) = cvt8(w6, w7);                                               \
        }                                                                                            \
        if ((H) + 3 < NT) {                                                                          \
            const float* p1  = gW1  + (size_t)((H) + 3) * 32;                                        \
            const float* p1b = gW1b + (size_t)((H) + 3) * 32;                                        \
            const float* p3  = gW3  + (size_t)((H) + 3) * 32;                                        \
            const float* p3b = gW3b + (size_t)((H) + 3) * 32;                                        \
            w0 = ((const float4*)p1)[0];  w1 = ((const float4*)p1)[1];                               \
            w2 = ((const float4*)p1b)[0]; w3 = ((const float4*)p1b)[1];                              \
            w4 = ((const float4*)p3)[0];  w5 = ((const float4*)p3)[1];                               \
            w6 = ((const float4*)p3b)[0]; w7 = ((const float4*)p3b)[1];                              \
        }                                                                                            \
        bf16x8 af[4], b1f[4], b3f[4];                                                                \
        _Pragma("unroll")                                                                            \
        for (int i = 0; i < 4; ++i) af[i]  = *(const bf16x8*)(&sA[S][aoff + i * 512]);               \
        _Pragma("unroll")                                                                            \
        for (int j = 0; j < 4; ++j) b1f[j] = *(const bf16x8*)(&sB1[S][boff + j * 512]);              \
        _Pragma("unroll")                                                                            \
        for (int j = 0; j < 4; ++j) b3f[j] = *(const bf16x8*)(&sB3[S][boff + j * 512]);              \
        if ((H) + 2 < NT) {                                                                          \
            async_cp16(gA0 + ((H) + 2) * 32, &sA[S2][dofsA0]);                                       \
            async_cp16(gA1 + ((H) + 2) * 32, &sA[S2][dofsA1]);                                       \
        }                                                                                            \
        __builtin_amdgcn_sched_barrier(0);                                                           \
        __builtin_amdgcn_s_setprio(1);                                                               \
        _Pragma("unroll")                                                                            \
        for (int i = 0; i < 4; ++i)                                                                  \
            _Pragma("unroll")                                                                        \
            for (int j = 0; j < 4; ++j)                                                              \
                accg[i][j] = __builtin_amdgcn_mfma_f32_16x16x32_bf16(af[i], b1f[j], accg[i][j], 0, 0, 0); \
        _Pragma("unroll")                                                                            \
        for (int i = 0; i < 4; ++i)                                                                  \
            _Pragma("unroll")                                                                        \
            for (int j = 0; j < 4; ++j)                                                              \
                accu[i][j] = __builtin_amdgcn_mfma_f32_16x16x32_bf16(af[i], b3f[j], accu[i][j], 0, 0, 0); \
        __builtin_amdgcn_s_setprio(0);                                                               \
        if ((H) + 1 < NT) {                                                                          \
            asm volatile("s_waitcnt lgkmcnt(0)" ::: "memory");                                       \
            if ((H) + 3 < NT)      asm volatile("s_waitcnt vmcnt(10)" ::: "memory");                 \
            else if ((H) + 2 < NT) asm volatile("s_waitcnt vmcnt(2)" ::: "memory");                  \
            else                   asm volatile("s_waitcnt vmcnt(0)" ::: "memory");                  \
            __builtin_amdgcn_s_barrier();                                                            \
            __builtin_amdgcn_sched_barrier(0);                                                       \
        }                                                                                            \
    }

    int h = 0;
    for (int t = 0; t < 21; ++t) {       // covers h = 0..62
        G1_PH(h,     0, 2);
        G1_PH(h + 1, 1, 0);
        G1_PH(h + 2, 2, 1);
        h += 3;
    }
    G1_PH(63, 0, 2);                      // 63 % 3 == 0
#undef G1_PH

    // epilogue: silu(gate)*up -> bf16
    #pragma unroll
    for (int i = 0; i < 4; ++i) {
        #pragma unroll
        for (int r = 0; r < 4; ++r) {
            int mloc = wm + i * 16 + q * 4 + r;
            int slot = mt * 128 + mloc;
            if (slot < ne) {
                size_t rowbase = (size_t)(off + slot) * I_DIM + nt * 128 + wn;
                #pragma unroll
                for (int j = 0; j < 4; ++j) {
                    float g = accg[i][j][r];
                    float u = accu[i][j][r];
                    float val = (g / (1.0f + __expf(-g))) * u;
                    hbuf[rowbase + j * 16 + c] = f2bf(val);
                }
            }
        }
    }
}

// GEMM2: out[tok] += wgt * (h[slot] @ W2^T). BM=128 x BN=128, 48KB, 3 blk/CU.
// Combine fused: exactly 2 commutative fp32 atomicAdds per out element;
// out is zeroed by the launcher's memset (replay-safe: memset is in-graph).
__global__ __launch_bounds__(256, 3)
void gemm2p_kernel(const unsigned short* __restrict__ hbuf,
                   const float* __restrict__ W2,
                   const int* __restrict__ counts,
                   const int* __restrict__ offsets,
                   const int* __restrict__ btok,
                   const float* __restrict__ bw,
                   float* __restrict__ out) {
    const int e = blockIdx.z;
    const int ne = counts[e];
    const int mt = blockIdx.y;
    if (mt * 128 >= ne) return;
    const int nt = blockIdx.x;
    const int off = offsets[e];

    __shared__ unsigned short sA[3][128 * 32];   // 24 KB
    __shared__ unsigned short sB[3][128 * 32];   // 24 KB -> 48 KB total

    const int tid = threadIdx.x;
    const int lane = tid & 63;
    const int wv = tid >> 6;
    const int wm = (wv >> 1) << 6;
    const int wn = (wv & 1) << 6;
    const int q = lane >> 4;
    const int c = lane & 15;
    const int xq = q ^ ((c >> 1) & 3);

    const int aoff = (wm + c) * 32 + xq * 8;
    const int boff = (wn + c) * 32 + xq * 8;

    const int arow = wv * 16 + (lane >> 2);
    const int sgA = (lane & 3) ^ ((lane >> 3) & 3);
    int sl0 = mt * 128 + arow;       if (sl0 >= ne) sl0 = ne - 1;
    int sl1 = mt * 128 + arow + 64;  if (sl1 >= ne) sl1 = ne - 1;
    const unsigned short* gA0 = hbuf + (size_t)(off + sl0) * I_DIM + sgA * 8;
    const unsigned short* gA1 = hbuf + (size_t)(off + sl1) * I_DIM + sgA * 8;
    const int dofsA0 = wv * 512;
    const int dofsA1 = 2048 + wv * 512;

    const int brow = tid >> 2;
    const int sgB = (tid & 3) ^ ((tid >> 3) & 3);
    const size_t wrow = (size_t)e * H_DIM + nt * 128 + brow;
    const float* gB  = W2 + wrow * I_DIM + (tid & 3) * 8;
    const float* gBb = gB + (size_t)64 * I_DIM;
    const int bwro  = brow * 32 + sgB * 8;
    const int bwro2 = bwro + 2048;

    f32x4 acc[4][4];
    const f32x4 zero = {0.0f, 0.0f, 0.0f, 0.0f};
    #pragma unroll
    for (int i = 0; i < 4; ++i)
        #pragma unroll
        for (int j = 0; j < 4; ++j) acc[i][j] = zero;

    float4 w0, w1, w2, w3;

    // ---- prologue ----
    #pragma unroll
    for (int h = 0; h < 2; ++h) {
        const float* p  = gB  + h * 32;
        const float* pb = gBb + h * 32;
        *(u16x8*)(&sB[h][bwro])  = cvt8(((const float4*)p)[0],  ((const float4*)p)[1]);
        *(u16x8*)(&sB[h][bwro2]) = cvt8(((const float4*)pb)[0], ((const float4*)pb)[1]);
    }
    async_cp16(gA0,      &sA[0][dofsA0]);
    async_cp16(gA1,      &sA[0][dofsA1]);
    async_cp16(gA0 + 32, &sA[1][dofsA0]);
    async_cp16(gA1 + 32, &sA[1][dofsA1]);
    w0 = ((const float4*)(gB  + 64))[0]; w1 = ((const float4*)(gB  + 64))[1];
    w2 = ((const float4*)(gBb + 64))[0]; w3 = ((const float4*)(gBb + 64))[1];

    asm volatile("s_waitcnt lgkmcnt(0)" ::: "memory");
    asm volatile("s_waitcnt vmcnt(6)" ::: "memory");
    __builtin_amdgcn_s_barrier();
    __builtin_amdgcn_sched_barrier(0);

    const int NT = I_DIM / 32;   // 128

#define G2_PH(H, S, S2)                                                                              \
    {                                                                                                \
        if ((H) + 2 < NT) {                                                                          \
            *(u16x8*)(&sB[S2][bwro])  = cvt8(w0, w1);                                                \
            *(u16x8*)(&sB[S2][bwro2]) = cvt8(w2, w3);                                                \
        }                                                                                            \
        if ((H) + 3 < NT) {                                                                          \
            const float* p  = gB  + (size_t)((H) + 3) * 32;                                          \
            const float* pb = gBb + (size_t)((H) + 3) * 32;                                          \
            w0 = ((const float4*)p)[0];  w1 = ((const float4*)p)[1];                                 \
            w2 = ((const float4*)pb)[0]; w3 = ((const float4*)pb)[1];                                \
        }                                                                                            \
        bf16x8 af[4], bfr[4];                                                                        \
        _Pragma("unroll")                                                                            \
        for (int i = 0; i < 4; ++i) af[i]  = *(const bf16x8*)(&sA[S][aoff + i * 512]);               \
        _Pragma("unroll")                                                                            \
        for (int j = 0; j < 4; ++j) bfr[j] = *(const bf16x8*)(&sB[S][boff + j * 512]);               \
        if ((H) + 2 < NT) {                                                                          \
            async_cp16(gA0 + ((H) + 2) * 32, &sA[S2][dofsA0]);                                       \
            async_cp16(gA1 + ((H) + 2) * 32, &sA[S2][dofsA1]);                                       \
        }                                                                                            \
        __builtin_amdgcn_sched_barrier(0);                                                           \
        __builtin_amdgcn_s_setprio(1);                                                               \
        _Pragma("unroll")                                                                            \
        for (int i = 0; i < 4; ++i)                                                                  \
            _Pragma("unroll")                                                                        \
            for (int j = 0; j < 4; ++j)                                                              \
                acc[i][j] = __builtin_amdgcn_mfma_f32_16x16x32_bf16(af[i], bfr[j], acc[i][j], 0, 0, 0); \
        __builtin_amdgcn_s_setprio(0);                                                               \
        if ((H) + 1 < NT) {                                                                          \
            asm volatile("s_waitcnt lgkmcnt(0)" ::: "memory");                                       \
            if ((H) + 3 < NT)      asm volatile("s_waitcnt vmcnt(6)" ::: "memory");                  \
            else if ((H) + 2 < NT) asm volatile("s_waitcnt vmcnt(2)" ::: "memory");                  \
            else                   asm volatile("s_waitcnt vmcnt(0)" ::: "memory");                  \
            __builtin_amdgcn_s_barrier();                                                            \
            __builtin_amdgcn_sched_barrier(0);                                                       \
        }                                                                                            \
    }

    int h = 0;
    for (int t = 0; t < 42; ++t) {       // covers h = 0..125
        G2_PH(h,     0, 2);
        G2_PH(h + 1, 1, 0);
        G2_PH(h + 2, 2, 1);
        h += 3;
    }
    G2_PH(126, 0, 2);                     // 126 % 3 == 0
    G2_PH(127, 1, 0);                     // 127 % 3 == 1
#undef G2_PH

    #pragma unroll
    for (int i = 0; i < 4; ++i) {
        #pragma unroll
        for (int r = 0; r < 4; ++r) {
            int mloc = wm + i * 16 + q * 4 + r;
            int slot = mt * 128 + mloc;
            if (slot < ne) {
                int tok = btok[off + slot];
                float wgt = bw[off + slot];
                float* obase = out + (size_t)tok * H_DIM + nt * 128 + wn;
                #pragma unroll
                for (int j = 0; j < 4; ++j)
                    atomicAdd(obase + j * 16 + c, wgt * acc[i][j][r]);
            }
        }
    }
}

// =====================  PATH B: fallback (fp32 weights in-loop) ==============

__global__ __launch_bounds__(256, 2)
void gemm1_kernel(const unsigned short* __restrict__ Xb,
                  const float* __restrict__ W1,
                  const float* __restrict__ W3,
                  const int* __restrict__ counts,
                  const int* __restrict__ offsets,
                  const int* __restrict__ btok,
                  unsigned short* __restrict__ hbuf) {
    const int e = blockIdx.z;
    const int ne = counts[e];
    const int mt = blockIdx.y;
    if (mt * 128 >= ne) return;
    const int nt = blockIdx.x;
    const int off = offsets[e];

    __shared__ unsigned short sA[128][32];
    __shared__ unsigned short sB1[128][32];
    __shared__ unsigned short sB3[128][32];
    __shared__ int s_tok[128];

    const int tid = threadIdx.x;
    if (tid < 128) {
        int slot = mt * 128 + tid;
        s_tok[tid] = (slot < ne) ? btok[off + slot] : -1;
    }

    const float* __restrict__ pB1 = W1 + (size_t)e * I_DIM * H_DIM + (size_t)(nt * 128) * H_DIM;
    const float* __restrict__ pB3 = W3 + (size_t)e * I_DIM * H_DIM + (size_t)(nt * 128) * H_DIM;

    const int lane = tid & 63;
    const int wv = tid >> 6;
    const int wm = (wv >> 1) << 6;
    const int wn = (wv & 1) << 6;
    const int q = lane >> 4;
    const int c = lane & 15;

    f32x4 accg[4][4], accu[4][4];
    const f32x4 zero = {0.0f, 0.0f, 0.0f, 0.0f};
    #pragma unroll
    for (int i = 0; i < 4; ++i)
        #pragma unroll
        for (int j = 0; j < 4; ++j) { accg[i][j] = zero; accu[i][j] = zero; }

    const int srow = tid >> 2;
    const int schunk = (tid & 3) * 8;

    for (int kt = 0; kt < H_DIM; kt += 32) {
        __syncthreads();
        #pragma unroll
        for (int p = 0; p < 2; ++p) {
            int r = srow + p * 64;
            int tok = s_tok[r];
            u16x8 av = {0, 0, 0, 0, 0, 0, 0, 0};
            if (tok >= 0)
                av = *(const u16x8*)(Xb + (size_t)tok * H_DIM + kt + schunk);
            *(u16x8*)(&sA[r][schunk]) = av;

            const float* b1 = pB1 + (size_t)r * H_DIM + kt + schunk;
            *(u16x8*)(&sB1[r][schunk]) = cvt8(*(const float4*)(b1), *(const float4*)(b1 + 4));

            const float* b3 = pB3 + (size_t)r * H_DIM + kt + schunk;
            *(u16x8*)(&sB3[r][schunk]) = cvt8(*(const float4*)(b3), *(const float4*)(b3 + 4));
        }
        __syncthreads();

        bf16x8 af[4], b1f[4], b3f[4];
        #pragma unroll
        for (int i = 0; i < 4; ++i)
            af[i] = *(const bf16x8*)(&sA[wm + i * 16 + c][q * 8]);
        #pragma unroll
        for (int j = 0; j < 4; ++j) {
            b1f[j] = *(const bf16x8*)(&sB1[wn + j * 16 + c][q * 8]);
            b3f[j] = *(const bf16x8*)(&sB3[wn + j * 16 + c][q * 8]);
        }
        #pragma unroll
        for (int i = 0; i < 4; ++i)
            #pragma unroll
            for (int j = 0; j < 4; ++j) {
                accg[i][j] = __builtin_amdgcn_mfma_f32_16x16x32_bf16(af[i], b1f[j], accg[i][j], 0, 0, 0);
                accu[i][j] = __builtin_amdgcn_mfma_f32_16x16x32_bf16(af[i], b3f[j], accu[i][j], 0, 0, 0);
            }
    }

    #pragma unroll
    for (int i = 0; i < 4; ++i) {
        #pragma unroll
        for (int r = 0; r < 4; ++r) {
            int mloc = wm + i * 16 + q * 4 + r;
            int slot = mt * 128 + mloc;
            if (slot < ne) {
                size_t rowbase = (size_t)(off + slot) * I_DIM + nt * 128 + wn;
                #pragma unroll
                for (int j = 0; j < 4; ++j) {
                    float g = accg[i][j][r];
                    float u = accu[i][j][r];
                    float val = (g / (1.0f + __expf(-g))) * u;
                    hbuf[rowbase + j * 16 + c] = f2bf(val);
                }
            }
        }
    }
}

__global__ __launch_bounds__(256, 2)
void gemm2_kernel(const unsigned short* __restrict__ hbuf,
                  const float* __restrict__ W2,
                  const int* __restrict__ counts,
                  const int* __restrict__ offsets,
                  const int* __restrict__ btok,
                  const float* __restrict__ bw,
                  float* __restrict__ out) {
    const int e = blockIdx.z;
    const int ne = counts[e];
    const int mt = blockIdx.y;
    if (mt * 128 >= ne) return;
    const int nt = blockIdx.x;
    const int off = offsets[e];

    __shared__ unsigned short sA[128][32];
    __shared__ unsigned short sB[128][32];

    const int tid = threadIdx.x;
    const int lane = tid & 63;
    const int wv = tid >> 6;
    const int wm = (wv >> 1) << 6;
    const int wn = (wv & 1) << 6;
    const int q = lane >> 4;
    const int c = lane & 15;

    const float* __restrict__ pB = W2 + (size_t)e * H_DIM * I_DIM + (size_t)(nt * 128) * I_DIM;

    f32x4 acc[4][4];
    const f32x4 zero = {0.0f, 0.0f, 0.0f, 0.0f};
    #pragma unroll
    for (int i = 0; i < 4; ++i)
        #pragma unroll
        for (int j = 0; j < 4; ++j) acc[i][j] = zero;

    const int srow = tid >> 2;
    const int schunk = (tid & 3) * 8;

    for (int kt = 0; kt < I_DIM; kt += 32) {
        __syncthreads();
        #pragma unroll
        for (int p = 0; p < 2; ++p) {
            int r = srow + p * 64;
            int slot = mt * 128 + r;
            u16x8 av = {0, 0, 0, 0, 0, 0, 0, 0};
            if (slot < ne)
                av = *(const u16x8*)(hbuf + (size_t)(off + slot) * I_DIM + kt + schunk);
            *(u16x8*)(&sA[r][schunk]) = av;

            const float* b = pB + (size_t)r * I_DIM + kt + schunk;
            *(u16x8*)(&sB[r][schunk]) = cvt8(*(const float4*)(b), *(const float4*)(b + 4));
        }
        __syncthreads();

        bf16x8 af[4], bfr[4];
        #pragma unroll
        for (int i = 0; i < 4; ++i)
            af[i] = *(const bf16x8*)(&sA[wm + i * 16 + c][q * 8]);
        #pragma unroll
        for (int j = 0; j < 4; ++j)
            bfr[j] = *(const bf16x8*)(&sB[wn + j * 16 + c][q * 8]);
        #pragma unroll
        for (int i = 0; i < 4; ++i)
            #pragma unroll
            for (int j = 0; j < 4; ++j)
                acc[i][j] = __builtin_amdgcn_mfma_f32_16x16x32_bf16(af[i], bfr[j], acc[i][j], 0, 0, 0);
    }

    #pragma unroll
    for (int i = 0; i < 4; ++i) {
        #pragma unroll
        for (int r = 0; r < 4; ++r) {
            int mloc = wm + i * 16 + q * 4 + r;
            int slot = mt * 128 + mloc;
            if (slot < ne) {
                int tok = btok[off + slot];
                float wgt = bw[off + slot];
                float* obase = out + (size_t)tok * H_DIM + nt * 128 + wn;
                #pragma unroll
                for (int j = 0; j < 4; ++j)
                    atomicAdd(obase + j * 16 + c, wgt * acc[i][j][r]);
            }
        }
    }
}

// ============================================================================

extern "C" void kernel_launch(void* const* d_in, const int* in_sizes, int n_in,
                              void* d_out, int out_size, void* d_ws, size_t ws_size,
                              hipStream_t stream) {
    const float* hs = (const float*)d_in[0];   // [T, H]
    const float* rl = (const float*)d_in[1];   // [T, E]
    const float* w1 = (const float*)d_in[2];   // [E, I, H]
    const float* w3 = (const float*)d_in[3];   // [E, I, H]
    const float* w2 = (const float*)d_in[4];   // [E, H, I]
    float* out = (float*)d_out;

    char* ws = (char*)d_ws;
    // meta region (first 1 MB)
    int*   counts   = (int*)(ws);
    int*   offsets  = (int*)(ws + 256);
    int*   btok     = (int*)(ws + 4096);            // 8192 ints
    float* bw       = (float*)(ws + 36864);         // 8192 floats
    int*   tok2slot = (int*)(ws + 69632);           // 8192 ints

    const size_t MB = 1ull << 20;
    const size_t NEED_A = 146 * MB;

    if (ws_size >= NEED_A) {
        // -------- Path A: fused-convert, multi-block/CU GEMMs ---------------
        unsigned short* Xb   = (unsigned short*)(ws + 1 * MB);     // 16 MB
        unsigned short* hbuf = (unsigned short*)(ws + 17 * MB);    // 64 MB

        hipMemsetAsync(out, 0, (size_t)T_TOK * H_DIM * sizeof(float), stream);

        routing_kernel<<<1, 256, 0, stream>>>(rl, counts, offsets, btok, bw, tok2slot);

        cvt_kernel<<<(T_TOK * H_DIM / 8) / 256, 256, 0, stream>>>(hs, Xb);

        gemm1p_kernel<<<dim3(I_DIM / 128, 64, N_EXP), 256, 0, stream>>>(
            Xb, w1, w3, counts, offsets, btok, hbuf);

        gemm2p_kernel<<<dim3(H_DIM / 128, 64, N_EXP), 256, 0, stream>>>(
            hbuf, w2, counts, offsets, btok, bw, out);
    } else {
        // -------- Path B: fallback (known-good round-1 structure) -----------
        unsigned short* Xb   = (unsigned short*)(ws + 1 * MB);            // 16 MB
        unsigned short* hbuf = (unsigned short*)(ws + 32 * MB);           // 64 MB

        hipMemsetAsync(out, 0, (size_t)T_TOK * H_DIM * sizeof(float), stream);

        routing_kernel<<<1, 256, 0, stream>>>(rl, counts, offsets, btok, bw, tok2slot);

        cvt_kernel<<<(T_TOK * H_DIM / 8) / 256, 256, 0, stream>>>(hs, Xb);

        gemm1_kernel<<<dim3(I_DIM / 128, T_TOK / 128, N_EXP), 256, 0, stream>>>(
            Xb, w1, w3, counts, offsets, btok, hbuf);

        gemm2_kernel<<<dim3(H_DIM / 128, T_TOK / 128, N_EXP), 256, 0, stream>>>(
            hbuf, w2, counts, offsets, btok, bw, out);
    }
}